// Round 2
// baseline (315.882 us; speedup 1.0000x reference)
//
#include <hip/hip_runtime.h>
#include <hip/hip_bf16.h>

#define NNODES 20000
#define NEDGES 320000
#define BATCH  2
#define D      128
#define EPSF   1e-5f
#define TILE   32
#define LDSROW 132   // 128 + 4 pad (keeps float4 16B alignment: 132*4=528=33*16)

static __device__ __forceinline__ float bf2f(__hip_bfloat16 v) { return __bfloat162float(v); }
static __device__ __forceinline__ unsigned short f2bf(float f) {
    __hip_bfloat16 h = __float2bfloat16(f);
    return *reinterpret_cast<unsigned short*>(&h);
}

// ---------------- CSR build ----------------

__global__ void hist_kernel(const int* __restrict__ dst, int* __restrict__ counts) {
    int e = blockIdx.x * blockDim.x + threadIdx.x;
    if (e < NEDGES) atomicAdd(&counts[dst[e]], 1);
}

__global__ __launch_bounds__(1024) void scan_kernel(const int* __restrict__ counts,
                                                    int* __restrict__ row_ptr,
                                                    int* __restrict__ cursor) {
    __shared__ int sd[1024];
    const int t = threadIdx.x;
    const int PER = (NNODES + 1023) / 1024;  // 20
    const int base = t * PER;
    int lsum = 0;
    for (int i = 0; i < PER; ++i) {
        int idx = base + i;
        if (idx < NNODES) lsum += counts[idx];
    }
    sd[t] = lsum;
    __syncthreads();
    for (int off = 1; off < 1024; off <<= 1) {
        int v = sd[t];
        int vp = (t >= off) ? sd[t - off] : 0;
        __syncthreads();
        sd[t] = v + vp;
        __syncthreads();
    }
    int run = sd[t] - lsum;  // exclusive prefix
    for (int i = 0; i < PER; ++i) {
        int idx = base + i;
        if (idx < NNODES) {
            row_ptr[idx] = run;
            cursor[idx]  = run;
            run += counts[idx];
        }
    }
    if (t == 1023) row_ptr[NNODES] = sd[1023];
}

__global__ void scatter_kernel(const int* __restrict__ src, const int* __restrict__ dst,
                               int* __restrict__ cursor, int* __restrict__ srcs) {
    int e = blockIdx.x * blockDim.x + threadIdx.x;
    if (e < NEDGES) {
        int p = atomicAdd(&cursor[dst[e]], 1);
        srcs[p] = src[e];
    }
}

// ---------------- fused per-node QKV ----------------
// h = x@Wp ; Hq = h@Wq+bq ; Hk = h@Wk+bk ; Hv = h@Wv+bv ; a = dot(Hq,Hk)*0.25
// stores h (bf16), Hv (bf16), a (f32). Block: 256 thr, 32 node-rows/block.

__global__ __launch_bounds__(256) void qkv_kernel(
    const float* __restrict__ x,
    const float* __restrict__ Wp,
    const float* __restrict__ Wq, const float* __restrict__ Bq,
    const float* __restrict__ Wk, const float* __restrict__ Bk,
    const float* __restrict__ Wv, const float* __restrict__ Bv,
    __hip_bfloat16* __restrict__ h_out,
    __hip_bfloat16* __restrict__ hv_out,
    float* __restrict__ a_out)
{
    __shared__ float xs[TILE][LDSROW];
    __shared__ float hs[TILE][LDSROW];
    const int t = threadIdx.x;
    const long row0 = (long)blockIdx.x * TILE;  // flat row into [B*N]

    // stage x tile (row-major, float4)
    {
        int i = t >> 3;
        int c = t & 7;
        const float* xr = x + (row0 + i) * D;
        #pragma unroll
        for (int cc = 0; cc < 4; ++cc) {
            int ch = c + cc * 8;  // 0..31 float4 chunks
            float4 v = *(const float4*)(xr + ch * 4);
            *(float4*)&xs[i][ch * 4] = v;
        }
    }
    __syncthreads();

    const int jg = t & 31, ig = t >> 5;
    const int j0 = jg * 4, i0 = ig * 4;

    // ---- m1: h = x @ Wp ----
    float acc[4][4];
    #pragma unroll
    for (int ii = 0; ii < 4; ++ii)
        #pragma unroll
        for (int jj = 0; jj < 4; ++jj) acc[ii][jj] = 0.f;
    for (int k = 0; k < D; ++k) {
        float4 wv4 = *(const float4*)(Wp + k * D + j0);
        float av[4] = { xs[i0][k], xs[i0 + 1][k], xs[i0 + 2][k], xs[i0 + 3][k] };
        float wq[4] = { wv4.x, wv4.y, wv4.z, wv4.w };
        #pragma unroll
        for (int ii = 0; ii < 4; ++ii)
            #pragma unroll
            for (int jj = 0; jj < 4; ++jj) acc[ii][jj] += av[ii] * wq[jj];
    }
    // epilogue: hs (fp32 for downstream matmuls) + h_out (bf16 for skip-gather)
    #pragma unroll
    for (int ii = 0; ii < 4; ++ii) {
        #pragma unroll
        for (int jj = 0; jj < 4; ++jj) hs[i0 + ii][j0 + jj] = acc[ii][jj];
        ushort4 pk;
        pk.x = f2bf(acc[ii][0]); pk.y = f2bf(acc[ii][1]);
        pk.z = f2bf(acc[ii][2]); pk.w = f2bf(acc[ii][3]);
        *(ushort4*)((unsigned short*)h_out + (row0 + i0 + ii) * D + j0) = pk;
    }
    __syncthreads();

    // ---- m2+m3: Hq, Hk (kept in regs), a = dot(Hq,Hk)*scale ----
    float aq[4][4], ak[4][4];
    #pragma unroll
    for (int ii = 0; ii < 4; ++ii)
        #pragma unroll
        for (int jj = 0; jj < 4; ++jj) { aq[ii][jj] = Bq[j0 + jj]; ak[ii][jj] = Bk[j0 + jj]; }
    for (int k = 0; k < D; ++k) {
        float4 wq4 = *(const float4*)(Wq + k * D + j0);
        float4 wk4 = *(const float4*)(Wk + k * D + j0);
        float av[4] = { hs[i0][k], hs[i0 + 1][k], hs[i0 + 2][k], hs[i0 + 3][k] };
        float q4[4] = { wq4.x, wq4.y, wq4.z, wq4.w };
        float k4[4] = { wk4.x, wk4.y, wk4.z, wk4.w };
        #pragma unroll
        for (int ii = 0; ii < 4; ++ii)
            #pragma unroll
            for (int jj = 0; jj < 4; ++jj) {
                aq[ii][jj] += av[ii] * q4[jj];
                ak[ii][jj] += av[ii] * k4[jj];
            }
    }
    {
        float ap[4];
        #pragma unroll
        for (int ii = 0; ii < 4; ++ii) {
            float s = 0.f;
            #pragma unroll
            for (int jj = 0; jj < 4; ++jj) s += aq[ii][jj] * ak[ii][jj];
            ap[ii] = s;
        }
        #pragma unroll
        for (int off = 1; off < 32; off <<= 1)
            #pragma unroll
            for (int ii = 0; ii < 4; ++ii) ap[ii] += __shfl_xor(ap[ii], off, 64);
        if (jg == 0)
            #pragma unroll
            for (int ii = 0; ii < 4; ++ii) a_out[row0 + i0 + ii] = ap[ii] * 0.25f;
    }

    // ---- m4: Hv = h @ Wv + bv ----
    #pragma unroll
    for (int ii = 0; ii < 4; ++ii)
        #pragma unroll
        for (int jj = 0; jj < 4; ++jj) acc[ii][jj] = Bv[j0 + jj];
    for (int k = 0; k < D; ++k) {
        float4 wv4 = *(const float4*)(Wv + k * D + j0);
        float av[4] = { hs[i0][k], hs[i0 + 1][k], hs[i0 + 2][k], hs[i0 + 3][k] };
        float v4[4] = { wv4.x, wv4.y, wv4.z, wv4.w };
        #pragma unroll
        for (int ii = 0; ii < 4; ++ii)
            #pragma unroll
            for (int jj = 0; jj < 4; ++jj) acc[ii][jj] += av[ii] * v4[jj];
    }
    #pragma unroll
    for (int ii = 0; ii < 4; ++ii) {
        ushort4 pk;
        pk.x = f2bf(acc[ii][0]); pk.y = f2bf(acc[ii][1]);
        pk.z = f2bf(acc[ii][2]); pk.w = f2bf(acc[ii][3]);
        *(ushort4*)((unsigned short*)hv_out + (row0 + i0 + ii) * D + j0) = pk;
    }
}

// ---------------- per-node aggregation: softmax + weighted V + skip + LN ----------------
// grid = B*NNODES blocks, 128 threads (one per channel)

__global__ __launch_bounds__(128) void agg_kernel(
    const __hip_bfloat16* __restrict__ hb,
    const __hip_bfloat16* __restrict__ hvb,
    const float* __restrict__ a,
    const int* __restrict__ row_ptr,
    const int* __restrict__ srcs,
    const float* __restrict__ ln_g, const float* __restrict__ ln_b,
    float* __restrict__ out)
{
    const int flat = blockIdx.x;
    const int n = flat % NNODES;
    const int b = flat / NNODES;
    const float* ab = a + (long)b * NNODES;
    const int e0 = row_ptr[n], e1 = row_ptr[n + 1];
    const int deg = e1 - e0;
    const int t = threadIdx.x;

    __shared__ float smax[2], ssum[2], s2[2], q2[2];
    __shared__ float wch[128];
    __shared__ int   sch[128];

    // pass 1: segment max
    float m = -1e30f;
    for (int e = e0 + t; e < e1; e += 128) m = fmaxf(m, ab[srcs[e]]);
    #pragma unroll
    for (int off = 32; off >= 1; off >>= 1) m = fmaxf(m, __shfl_xor(m, off, 64));
    if ((t & 63) == 0) smax[t >> 6] = m;
    __syncthreads();
    m = fmaxf(smax[0], smax[1]);

    // pass 2: sum of exp
    float s = 0.f;
    for (int e = e0 + t; e < e1; e += 128) s += __expf(ab[srcs[e]] - m);
    #pragma unroll
    for (int off = 32; off >= 1; off >>= 1) s += __shfl_xor(s, off, 64);
    if ((t & 63) == 0) ssum[t >> 6] = s;
    __syncthreads();
    s = ssum[0] + ssum[1];
    const float inv_s = (deg > 0) ? 1.f / s : 0.f;

    // pass 3: chunked weighted accumulation (thread t = channel t)
    const long rowbase = (long)b * NNODES;
    float acc = 0.f, sk = 0.f;
    const int c = t;
    for (int base = e0; base < e1; base += 128) {
        int cnt = min(128, e1 - base);
        __syncthreads();
        if (t < cnt) {
            int sr = srcs[base + t];
            sch[t] = sr;
            wch[t] = __expf(ab[sr] - m) * inv_s;
        }
        __syncthreads();
        for (int q = 0; q < cnt; ++q) {
            long rb = (rowbase + sch[q]) * (long)D + c;
            acc += wch[q] * bf2f(hvb[rb]);
            sk  += bf2f(hb[rb]);
        }
    }
    float v = acc + sk * (1.f / (float)max(deg, 1));

    // fused LayerNorm over 128 channels
    float sum = v, sq = v * v;
    #pragma unroll
    for (int off = 32; off >= 1; off >>= 1) {
        sum += __shfl_xor(sum, off, 64);
        sq  += __shfl_xor(sq, off, 64);
    }
    if ((t & 63) == 0) { s2[t >> 6] = sum; q2[t >> 6] = sq; }
    __syncthreads();
    sum = s2[0] + s2[1];
    sq  = q2[0] + q2[1];
    float mu  = sum * (1.f / 128.f);
    float var = sq * (1.f / 128.f) - mu * mu;
    out[(long)flat * D + c] = (v - mu) * rsqrtf(var + EPSF) * ln_g[c] + ln_b[c];
}

// ---------------- launch ----------------

extern "C" void kernel_launch(void* const* d_in, const int* in_sizes, int n_in,
                              void* d_out, int out_size, void* d_ws, size_t ws_size,
                              hipStream_t stream)
{
    const float* x    = (const float*)d_in[0];
    const float* Wp   = (const float*)d_in[1];
    const float* Wq   = (const float*)d_in[2];
    const float* Bq   = (const float*)d_in[3];
    const float* Wk   = (const float*)d_in[4];
    const float* Bk   = (const float*)d_in[5];
    const float* Wv   = (const float*)d_in[6];
    const float* Bv   = (const float*)d_in[7];
    const float* ln_g = (const float*)d_in[8];
    const float* ln_b = (const float*)d_in[9];
    const int*   ei   = (const int*)d_in[10];
    const int* esrc = ei;
    const int* edst = ei + NEDGES;
    float* out = (float*)d_out;

    char* p = (char*)d_ws;
    auto alloc = [&](size_t bytes) -> char* {
        char* r = p;
        p += (bytes + 255) & ~(size_t)255;
        return r;
    };
    __hip_bfloat16* hb  = (__hip_bfloat16*)alloc((size_t)BATCH * NNODES * D * 2);
    __hip_bfloat16* hvb = (__hip_bfloat16*)alloc((size_t)BATCH * NNODES * D * 2);
    float* a      = (float*)alloc((size_t)BATCH * NNODES * 4);
    int* counts   = (int*)alloc((size_t)NNODES * 4);
    int* row_ptr  = (int*)alloc((size_t)(NNODES + 1) * 4);
    int* cursor   = (int*)alloc((size_t)NNODES * 4);
    int* srcs     = (int*)alloc((size_t)NEDGES * 4);

    hipMemsetAsync(counts, 0, (size_t)NNODES * 4, stream);
    hist_kernel<<<(NEDGES + 255) / 256, 256, 0, stream>>>(edst, counts);
    scan_kernel<<<1, 1024, 0, stream>>>(counts, row_ptr, cursor);
    scatter_kernel<<<(NEDGES + 255) / 256, 256, 0, stream>>>(esrc, edst, cursor, srcs);
    qkv_kernel<<<(BATCH * NNODES) / TILE, 256, 0, stream>>>(x, Wp, Wq, Bq, Wk, Bk, Wv, Bv, hb, hvb, a);
    agg_kernel<<<BATCH * NNODES, 128, 0, stream>>>(hb, hvb, a, row_ptr, srcs, ln_g, ln_b, out);
}

// Round 4
// 273.214 us; speedup vs baseline: 1.1562x; 1.1562x over previous
//
#include <hip/hip_runtime.h>
#include <hip/hip_bf16.h>

#define NNODES 20000
#define NEDGES 320000
#define BATCH  2
#define D      128
#define EPSF   1e-5f
#define QTILE_M 64
#define XS_LD   136   // ushorts per LDS row: 128 + 8 pad (272 B stride -> 2-way bank alias, free)

typedef __attribute__((ext_vector_type(8))) short bf16x8;
typedef __attribute__((ext_vector_type(4))) float f32x4;

static __device__ __forceinline__ float bf2f(__hip_bfloat16 v) { return __bfloat162float(v); }
static __device__ __forceinline__ unsigned short f2bf(float f) {
    __hip_bfloat16 h = __float2bfloat16(f);
    return *reinterpret_cast<unsigned short*>(&h);
}

// ---------------- CSR build ----------------

__global__ void hist_kernel(const int* __restrict__ dst, int* __restrict__ counts) {
    int e = blockIdx.x * blockDim.x + threadIdx.x;
    if (e < NEDGES) atomicAdd(&counts[dst[e]], 1);
}

__global__ __launch_bounds__(1024) void scan_kernel(const int* __restrict__ counts,
                                                    int* __restrict__ row_ptr,
                                                    int* __restrict__ cursor) {
    __shared__ int sd[1024];
    const int t = threadIdx.x;
    const int PER = (NNODES + 1023) / 1024;  // 20
    const int base = t * PER;
    int lsum = 0;
    for (int i = 0; i < PER; ++i) {
        int idx = base + i;
        if (idx < NNODES) lsum += counts[idx];
    }
    sd[t] = lsum;
    __syncthreads();
    for (int off = 1; off < 1024; off <<= 1) {
        int v = sd[t];
        int vp = (t >= off) ? sd[t - off] : 0;
        __syncthreads();
        sd[t] = v + vp;
        __syncthreads();
    }
    int run = sd[t] - lsum;  // exclusive prefix
    for (int i = 0; i < PER; ++i) {
        int idx = base + i;
        if (idx < NNODES) {
            row_ptr[idx] = run;
            cursor[idx]  = run;
            run += counts[idx];
        }
    }
    if (t == 1023) row_ptr[NNODES] = sd[1023];
}

__global__ void scatter_kernel(const int* __restrict__ src, const int* __restrict__ dst,
                               int* __restrict__ cursor, int* __restrict__ srcs) {
    int e = blockIdx.x * blockDim.x + threadIdx.x;
    if (e < NEDGES) {
        int p = atomicAdd(&cursor[dst[e]], 1);
        srcs[p] = src[e];
    }
}

// ---------------- weight prep: fp32 [K][N] -> bf16 transposed [N][K], 4 matrices ----------------

__global__ __launch_bounds__(256) void prep_kernel(
    const float* __restrict__ Wp, const float* __restrict__ Wq,
    const float* __restrict__ Wk, const float* __restrict__ Wv,
    unsigned short* __restrict__ WT)
{
    int id = blockIdx.x * 256 + threadIdx.x;  // 0..65535
    int mat = id >> 14, rem = id & 16383;
    int n = rem >> 7, k = rem & 127;
    const float* W = (mat == 0) ? Wp : (mat == 1) ? Wq : (mat == 2) ? Wk : Wv;
    WT[mat * 16384 + n * 128 + k] = f2bf(W[k * 128 + n]);
}

// ---------------- fused per-node QKV via bf16 MFMA ----------------
// h = x@Wp ; Q = h@Wq+bq ; K = h@Wk+bk ; V = h@Wv+bv ; a = dot(Q,K)*0.25
// Block: 256 thr (4 waves), 64 rows/block, each wave computes 16 rows x 128 cols.
// mfma_f32_16x16x32_bf16 layouts: A: lane l -> row=l&15, k=8*(l>>4)+i (contiguous 8 bf16)
//                                 B: lane l -> col=l&15, k=8*(l>>4)+i (from W^T, contiguous)
//                                 C/D: lane l -> col=l&15, row=4*(l>>4)+i

__global__ __launch_bounds__(256) void qkv_mfma_kernel(
    const float* __restrict__ x,
    const unsigned short* __restrict__ WT,  // 4 x [128][128] bf16: Wp^T, Wq^T, Wk^T, Wv^T
    const float* __restrict__ Bq, const float* __restrict__ Bk, const float* __restrict__ Bv,
    unsigned short* __restrict__ h_out,
    unsigned short* __restrict__ hv_out,
    float* __restrict__ a_out)
{
    __shared__ unsigned short Xs[QTILE_M][XS_LD];
    __shared__ unsigned short Hs[QTILE_M][XS_LD];
    const int t = threadIdx.x;
    const long row0 = (long)blockIdx.x * QTILE_M;  // flat row into [B*N]

    const unsigned short* WpT = WT;
    const unsigned short* WqT = WT + 16384;
    const unsigned short* WkT = WT + 32768;
    const unsigned short* WvT = WT + 49152;

    // ---- stage x (fp32) -> Xs (bf16) ----
    #pragma unroll
    for (int q = 0; q < 8; ++q) {
        int ch = t + q * 256;               // 2048 float4 chunks (64 rows x 32)
        int r = ch >> 5, c4 = (ch & 31) << 2;
        float4 v = *(const float4*)(x + (row0 + r) * D + c4);
        ushort4 pk = { f2bf(v.x), f2bf(v.y), f2bf(v.z), f2bf(v.w) };
        *(ushort4*)&Xs[r][c4] = pk;
    }
    __syncthreads();

    const int w  = t >> 6;       // wave 0..3
    const int l  = t & 63;
    const int g  = l >> 4;       // 0..3
    const int c  = l & 15;       // 0..15
    const int rw = w * 16;       // wave's row base within tile

    // ---- A-fragments of x from LDS ----
    bf16x8 ax[4];
    #pragma unroll
    for (int ks = 0; ks < 4; ++ks)
        ax[ks] = *(const bf16x8*)&Xs[rw + c][ks * 32 + g * 8];

    // ---- m1: h = x @ Wp ----
    f32x4 hacc[8];
    #pragma unroll
    for (int nt = 0; nt < 8; ++nt) hacc[nt] = f32x4{0.f, 0.f, 0.f, 0.f};
    #pragma unroll
    for (int nt = 0; nt < 8; ++nt)
        #pragma unroll
        for (int ks = 0; ks < 4; ++ks) {
            bf16x8 b = *(const bf16x8*)(WpT + (nt * 16 + c) * D + ks * 32 + g * 8);
            hacc[nt] = __builtin_amdgcn_mfma_f32_16x16x32_bf16(ax[ks], b, hacc[nt], 0, 0, 0);
        }
    // write h tile to LDS (bf16)
    #pragma unroll
    for (int nt = 0; nt < 8; ++nt)
        #pragma unroll
        for (int i = 0; i < 4; ++i)
            Hs[rw + 4 * g + i][nt * 16 + c] = f2bf(hacc[nt][i]);
    __syncthreads();

    // ---- copy h tile LDS -> global (coalesced 16B) ----
    #pragma unroll
    for (int q = 0; q < 4; ++q) {
        int ch = t + q * 256;               // 1024 chunks of 8 ushorts
        int r = ch >> 4, off = (ch & 15) << 3;
        *(bf16x8*)(h_out + (row0 + r) * D + off) = *(const bf16x8*)&Hs[r][off];
    }

    // ---- A-fragments of h from LDS ----
    bf16x8 ah[4];
    #pragma unroll
    for (int ks = 0; ks < 4; ++ks)
        ah[ks] = *(const bf16x8*)&Hs[rw + c][ks * 32 + g * 8];

    // ---- m2+m3: Q = h@Wq+bq, K = h@Wk+bk (in regs), alpha = dot(Q,K)*0.25 ----
    f32x4 qacc[8], kacc[8];
    #pragma unroll
    for (int nt = 0; nt < 8; ++nt) {
        qacc[nt] = f32x4{0.f, 0.f, 0.f, 0.f};
        kacc[nt] = f32x4{0.f, 0.f, 0.f, 0.f};
    }
    #pragma unroll
    for (int nt = 0; nt < 8; ++nt)
        #pragma unroll
        for (int ks = 0; ks < 4; ++ks) {
            bf16x8 bq = *(const bf16x8*)(WqT + (nt * 16 + c) * D + ks * 32 + g * 8);
            bf16x8 bk = *(const bf16x8*)(WkT + (nt * 16 + c) * D + ks * 32 + g * 8);
            qacc[nt] = __builtin_amdgcn_mfma_f32_16x16x32_bf16(ah[ks], bq, qacc[nt], 0, 0, 0);
            kacc[nt] = __builtin_amdgcn_mfma_f32_16x16x32_bf16(ah[ks], bk, kacc[nt], 0, 0, 0);
        }
    {
        float p[4] = {0.f, 0.f, 0.f, 0.f};
        #pragma unroll
        for (int nt = 0; nt < 8; ++nt) {
            float bq = Bq[nt * 16 + c];
            float bk = Bk[nt * 16 + c];
            #pragma unroll
            for (int i = 0; i < 4; ++i)
                p[i] += (qacc[nt][i] + bq) * (kacc[nt][i] + bk);
        }
        #pragma unroll
        for (int off = 1; off < 16; off <<= 1)
            #pragma unroll
            for (int i = 0; i < 4; ++i) p[i] += __shfl_xor(p[i], off, 64);
        if (c == 0)
            #pragma unroll
            for (int i = 0; i < 4; ++i)
                a_out[row0 + rw + 4 * g + i] = p[i] * 0.25f;
    }

    // ---- m4: V = h @ Wv + bv ----
    f32x4 vacc[8];
    #pragma unroll
    for (int nt = 0; nt < 8; ++nt) vacc[nt] = f32x4{0.f, 0.f, 0.f, 0.f};
    #pragma unroll
    for (int nt = 0; nt < 8; ++nt)
        #pragma unroll
        for (int ks = 0; ks < 4; ++ks) {
            bf16x8 b = *(const bf16x8*)(WvT + (nt * 16 + c) * D + ks * 32 + g * 8);
            vacc[nt] = __builtin_amdgcn_mfma_f32_16x16x32_bf16(ah[ks], b, vacc[nt], 0, 0, 0);
        }
    // V tile into Xs (x is dead), bias added in fp32
    #pragma unroll
    for (int nt = 0; nt < 8; ++nt) {
        float bv = Bv[nt * 16 + c];
        #pragma unroll
        for (int i = 0; i < 4; ++i)
            Xs[rw + 4 * g + i][nt * 16 + c] = f2bf(vacc[nt][i] + bv);
    }
    __syncthreads();

    // ---- copy V tile LDS -> global ----
    #pragma unroll
    for (int q = 0; q < 4; ++q) {
        int ch = t + q * 256;
        int r = ch >> 4, off = (ch & 15) << 3;
        *(bf16x8*)(hv_out + (row0 + r) * D + off) = *(const bf16x8*)&Xs[r][off];
    }
}

// ---------------- per-node aggregation: softmax + weighted V + skip + LN ----------------
// grid = B*NNODES blocks, 128 threads (one per channel)

__global__ __launch_bounds__(128) void agg_kernel(
    const __hip_bfloat16* __restrict__ hb,
    const __hip_bfloat16* __restrict__ hvb,
    const float* __restrict__ a,
    const int* __restrict__ row_ptr,
    const int* __restrict__ srcs,
    const float* __restrict__ ln_g, const float* __restrict__ ln_b,
    float* __restrict__ out)
{
    const int flat = blockIdx.x;
    const int n = flat % NNODES;
    const int b = flat / NNODES;
    const float* ab = a + (long)b * NNODES;
    const int e0 = row_ptr[n], e1 = row_ptr[n + 1];
    const int deg = e1 - e0;
    const int t = threadIdx.x;

    __shared__ float smax[2], ssum[2], s2[2], q2[2];
    __shared__ float wch[128];
    __shared__ int   sch[128];

    // pass 1: segment max
    float m = -1e30f;
    for (int e = e0 + t; e < e1; e += 128) m = fmaxf(m, ab[srcs[e]]);
    #pragma unroll
    for (int off = 32; off >= 1; off >>= 1) m = fmaxf(m, __shfl_xor(m, off, 64));
    if ((t & 63) == 0) smax[t >> 6] = m;
    __syncthreads();
    m = fmaxf(smax[0], smax[1]);

    // pass 2: sum of exp
    float s = 0.f;
    for (int e = e0 + t; e < e1; e += 128) s += __expf(ab[srcs[e]] - m);
    #pragma unroll
    for (int off = 32; off >= 1; off >>= 1) s += __shfl_xor(s, off, 64);
    if ((t & 63) == 0) ssum[t >> 6] = s;
    __syncthreads();
    s = ssum[0] + ssum[1];
    const float inv_s = (deg > 0) ? 1.f / s : 0.f;

    // pass 3: chunked weighted accumulation (thread t = channel t)
    const long rowbase = (long)b * NNODES;
    float acc = 0.f, sk = 0.f;
    const int c = t;
    for (int base = e0; base < e1; base += 128) {
        int cnt = min(128, e1 - base);
        __syncthreads();
        if (t < cnt) {
            int sr = srcs[base + t];
            sch[t] = sr;
            wch[t] = __expf(ab[sr] - m) * inv_s;
        }
        __syncthreads();
        for (int q = 0; q < cnt; ++q) {
            long rb = (rowbase + sch[q]) * (long)D + c;
            acc += wch[q] * bf2f(hvb[rb]);
            sk  += bf2f(hb[rb]);
        }
    }
    float v = acc + sk * (1.f / (float)max(deg, 1));

    // fused LayerNorm over 128 channels
    float sum = v, sq = v * v;
    #pragma unroll
    for (int off = 32; off >= 1; off >>= 1) {
        sum += __shfl_xor(sum, off, 64);
        sq  += __shfl_xor(sq, off, 64);
    }
    if ((t & 63) == 0) { s2[t >> 6] = sum; q2[t >> 6] = sq; }
    __syncthreads();
    sum = s2[0] + s2[1];
    sq  = q2[0] + q2[1];
    float mu  = sum * (1.f / 128.f);
    float var = sq * (1.f / 128.f) - mu * mu;
    out[(long)flat * D + c] = (v - mu) * rsqrtf(var + EPSF) * ln_g[c] + ln_b[c];
}

// ---------------- launch ----------------

extern "C" void kernel_launch(void* const* d_in, const int* in_sizes, int n_in,
                              void* d_out, int out_size, void* d_ws, size_t ws_size,
                              hipStream_t stream)
{
    const float* x    = (const float*)d_in[0];
    const float* Wp   = (const float*)d_in[1];
    const float* Wq   = (const float*)d_in[2];
    const float* Bq   = (const float*)d_in[3];
    const float* Wk   = (const float*)d_in[4];
    const float* Bk   = (const float*)d_in[5];
    const float* Wv   = (const float*)d_in[6];
    const float* Bv   = (const float*)d_in[7];
    const float* ln_g = (const float*)d_in[8];
    const float* ln_b = (const float*)d_in[9];
    const int*   ei   = (const int*)d_in[10];
    const int* esrc = ei;
    const int* edst = ei + NEDGES;
    float* out = (float*)d_out;

    char* p = (char*)d_ws;
    auto alloc = [&](size_t bytes) -> char* {
        char* r = p;
        p += (bytes + 255) & ~(size_t)255;
        return r;
    };
    __hip_bfloat16* hb  = (__hip_bfloat16*)alloc((size_t)BATCH * NNODES * D * 2);
    __hip_bfloat16* hvb = (__hip_bfloat16*)alloc((size_t)BATCH * NNODES * D * 2);
    float* a      = (float*)alloc((size_t)BATCH * NNODES * 4);
    int* counts   = (int*)alloc((size_t)NNODES * 4);
    int* row_ptr  = (int*)alloc((size_t)(NNODES + 1) * 4);
    int* cursor   = (int*)alloc((size_t)NNODES * 4);
    int* srcs     = (int*)alloc((size_t)NEDGES * 4);
    unsigned short* WT = (unsigned short*)alloc((size_t)4 * 128 * 128 * 2);

    hipMemsetAsync(counts, 0, (size_t)NNODES * 4, stream);
    prep_kernel<<<256, 256, 0, stream>>>(Wp, Wq, Wk, Wv, WT);
    hist_kernel<<<(NEDGES + 255) / 256, 256, 0, stream>>>(edst, counts);
    scan_kernel<<<1, 1024, 0, stream>>>(counts, row_ptr, cursor);
    scatter_kernel<<<(NEDGES + 255) / 256, 256, 0, stream>>>(esrc, edst, cursor, srcs);
    qkv_mfma_kernel<<<(BATCH * NNODES) / QTILE_M, 256, 0, stream>>>(
        x, WT, Bq, Bk, Bv, (unsigned short*)hb, (unsigned short*)hvb, a);
    agg_kernel<<<BATCH * NNODES, 128, 0, stream>>>(hb, hvb, a, row_ptr, srcs, ln_g, ln_b, out);
}

// Round 5
// 255.194 us; speedup vs baseline: 1.2378x; 1.0706x over previous
//
#include <hip/hip_runtime.h>
#include <hip/hip_bf16.h>

#define NNODES 20000
#define NEDGES 320000
#define BATCH  2
#define D      128
#define EPSF   1e-5f
#define QTILE_M 64
#define XS_LD   136   // ushorts per LDS row: 128 + 8 pad (272 B stride -> 2-way bank alias, free)

typedef __attribute__((ext_vector_type(8))) short bf16x8;
typedef __attribute__((ext_vector_type(4))) float f32x4;

static __device__ __forceinline__ float bf2f(__hip_bfloat16 v) { return __bfloat162float(v); }
static __device__ __forceinline__ unsigned short f2bf(float f) {
    __hip_bfloat16 h = __float2bfloat16(f);
    return *reinterpret_cast<unsigned short*>(&h);
}
static __device__ __forceinline__ float bfu(unsigned short u) {
    union { unsigned int i; float f; } c;
    c.i = ((unsigned int)u) << 16;
    return c.f;
}

// ---------------- CSR build + weight prep ----------------

// blocks [0,256): transpose 4 weight mats fp32 [K][N] -> bf16 [N][K]
// blocks [256,1506): histogram of dst
__global__ __launch_bounds__(256) void prep_hist_kernel(
    const float* __restrict__ Wp, const float* __restrict__ Wq,
    const float* __restrict__ Wk, const float* __restrict__ Wv,
    unsigned short* __restrict__ WT,
    const int* __restrict__ dst, int* __restrict__ counts)
{
    int bid = blockIdx.x;
    if (bid < 256) {
        int id = bid * 256 + threadIdx.x;  // 0..65535
        int mat = id >> 14, rem = id & 16383;
        int n = rem >> 7, k = rem & 127;
        const float* W = (mat == 0) ? Wp : (mat == 1) ? Wq : (mat == 2) ? Wk : Wv;
        WT[mat * 16384 + n * 128 + k] = f2bf(W[k * 128 + n]);
    } else {
        int e = (bid - 256) * 256 + threadIdx.x;
        if (e < NEDGES) atomicAdd(&counts[dst[e]], 1);
    }
}

__global__ __launch_bounds__(1024) void scan_kernel(const int* __restrict__ counts,
                                                    int* __restrict__ row_ptr,
                                                    int* __restrict__ cursor) {
    __shared__ int sd[1024];
    const int t = threadIdx.x;
    const int PER = (NNODES + 1023) / 1024;  // 20
    const int base = t * PER;
    int lsum = 0;
    for (int i = 0; i < PER; ++i) {
        int idx = base + i;
        if (idx < NNODES) lsum += counts[idx];
    }
    sd[t] = lsum;
    __syncthreads();
    for (int off = 1; off < 1024; off <<= 1) {
        int v = sd[t];
        int vp = (t >= off) ? sd[t - off] : 0;
        __syncthreads();
        sd[t] = v + vp;
        __syncthreads();
    }
    int run = sd[t] - lsum;  // exclusive prefix
    for (int i = 0; i < PER; ++i) {
        int idx = base + i;
        if (idx < NNODES) {
            row_ptr[idx] = run;
            cursor[idx]  = run;
            run += counts[idx];
        }
    }
    if (t == 1023) row_ptr[NNODES] = sd[1023];
}

__global__ void scatter_kernel(const int* __restrict__ src, const int* __restrict__ dst,
                               int* __restrict__ cursor, int* __restrict__ srcs) {
    int e = blockIdx.x * blockDim.x + threadIdx.x;
    if (e < NEDGES) {
        int p = atomicAdd(&cursor[dst[e]], 1);
        srcs[p] = src[e];
    }
}

// ---------------- fused per-node QKV via bf16 MFMA ----------------
// h = x@Wp ; Q = h@Wq+bq ; K = h@Wk+bk ; V = h@Wv+bv ; a = dot(Q,K)*0.25
// Block: 256 thr (4 waves), 64 rows/block, each wave computes 16 rows x 128 cols.

__global__ __launch_bounds__(256) void qkv_mfma_kernel(
    const float* __restrict__ x,
    const unsigned short* __restrict__ WT,  // 4 x [128][128] bf16: Wp^T, Wq^T, Wk^T, Wv^T
    const float* __restrict__ Bq, const float* __restrict__ Bk, const float* __restrict__ Bv,
    unsigned short* __restrict__ h_out,
    unsigned short* __restrict__ hv_out,
    float* __restrict__ a_out)
{
    __shared__ unsigned short Xs[QTILE_M][XS_LD];
    __shared__ unsigned short Hs[QTILE_M][XS_LD];
    const int t = threadIdx.x;
    const long row0 = (long)blockIdx.x * QTILE_M;  // flat row into [B*N]

    const unsigned short* WpT = WT;
    const unsigned short* WqT = WT + 16384;
    const unsigned short* WkT = WT + 32768;
    const unsigned short* WvT = WT + 49152;

    // ---- stage x (fp32) -> Xs (bf16) ----
    #pragma unroll
    for (int q = 0; q < 8; ++q) {
        int ch = t + q * 256;               // 2048 float4 chunks (64 rows x 32)
        int r = ch >> 5, c4 = (ch & 31) << 2;
        float4 v = *(const float4*)(x + (row0 + r) * D + c4);
        ushort4 pk = { f2bf(v.x), f2bf(v.y), f2bf(v.z), f2bf(v.w) };
        *(ushort4*)&Xs[r][c4] = pk;
    }
    __syncthreads();

    const int w  = t >> 6;       // wave 0..3
    const int l  = t & 63;
    const int g  = l >> 4;       // 0..3
    const int c  = l & 15;       // 0..15
    const int rw = w * 16;       // wave's row base within tile

    // ---- A-fragments of x from LDS ----
    bf16x8 ax[4];
    #pragma unroll
    for (int ks = 0; ks < 4; ++ks)
        ax[ks] = *(const bf16x8*)&Xs[rw + c][ks * 32 + g * 8];

    // ---- m1: h = x @ Wp ----
    f32x4 hacc[8];
    #pragma unroll
    for (int nt = 0; nt < 8; ++nt) hacc[nt] = f32x4{0.f, 0.f, 0.f, 0.f};
    #pragma unroll
    for (int nt = 0; nt < 8; ++nt)
        #pragma unroll
        for (int ks = 0; ks < 4; ++ks) {
            bf16x8 b = *(const bf16x8*)(WpT + (nt * 16 + c) * D + ks * 32 + g * 8);
            hacc[nt] = __builtin_amdgcn_mfma_f32_16x16x32_bf16(ax[ks], b, hacc[nt], 0, 0, 0);
        }
    // write h tile to LDS (bf16)
    #pragma unroll
    for (int nt = 0; nt < 8; ++nt)
        #pragma unroll
        for (int i = 0; i < 4; ++i)
            Hs[rw + 4 * g + i][nt * 16 + c] = f2bf(hacc[nt][i]);
    __syncthreads();

    // ---- copy h tile LDS -> global (coalesced 16B) ----
    #pragma unroll
    for (int q = 0; q < 4; ++q) {
        int ch = t + q * 256;               // 1024 chunks of 8 ushorts
        int r = ch >> 4, off = (ch & 15) << 3;
        *(bf16x8*)(h_out + (row0 + r) * D + off) = *(const bf16x8*)&Hs[r][off];
    }

    // ---- A-fragments of h from LDS ----
    bf16x8 ah[4];
    #pragma unroll
    for (int ks = 0; ks < 4; ++ks)
        ah[ks] = *(const bf16x8*)&Hs[rw + c][ks * 32 + g * 8];

    // ---- m2+m3: Q = h@Wq+bq, K = h@Wk+bk (in regs), alpha = dot(Q,K)*0.25 ----
    f32x4 qacc[8], kacc[8];
    #pragma unroll
    for (int nt = 0; nt < 8; ++nt) {
        qacc[nt] = f32x4{0.f, 0.f, 0.f, 0.f};
        kacc[nt] = f32x4{0.f, 0.f, 0.f, 0.f};
    }
    #pragma unroll
    for (int nt = 0; nt < 8; ++nt)
        #pragma unroll
        for (int ks = 0; ks < 4; ++ks) {
            bf16x8 bq = *(const bf16x8*)(WqT + (nt * 16 + c) * D + ks * 32 + g * 8);
            bf16x8 bk = *(const bf16x8*)(WkT + (nt * 16 + c) * D + ks * 32 + g * 8);
            qacc[nt] = __builtin_amdgcn_mfma_f32_16x16x32_bf16(ah[ks], bq, qacc[nt], 0, 0, 0);
            kacc[nt] = __builtin_amdgcn_mfma_f32_16x16x32_bf16(ah[ks], bk, kacc[nt], 0, 0, 0);
        }
    {
        float p[4] = {0.f, 0.f, 0.f, 0.f};
        #pragma unroll
        for (int nt = 0; nt < 8; ++nt) {
            float bq = Bq[nt * 16 + c];
            float bk = Bk[nt * 16 + c];
            #pragma unroll
            for (int i = 0; i < 4; ++i)
                p[i] += (qacc[nt][i] + bq) * (kacc[nt][i] + bk);
        }
        #pragma unroll
        for (int off = 1; off < 16; off <<= 1)
            #pragma unroll
            for (int i = 0; i < 4; ++i) p[i] += __shfl_xor(p[i], off, 64);
        if (c == 0)
            #pragma unroll
            for (int i = 0; i < 4; ++i)
                a_out[row0 + rw + 4 * g + i] = p[i] * 0.25f;
    }

    // ---- m4: V = h @ Wv + bv ----
    f32x4 vacc[8];
    #pragma unroll
    for (int nt = 0; nt < 8; ++nt) vacc[nt] = f32x4{0.f, 0.f, 0.f, 0.f};
    #pragma unroll
    for (int nt = 0; nt < 8; ++nt)
        #pragma unroll
        for (int ks = 0; ks < 4; ++ks) {
            bf16x8 b = *(const bf16x8*)(WvT + (nt * 16 + c) * D + ks * 32 + g * 8);
            vacc[nt] = __builtin_amdgcn_mfma_f32_16x16x32_bf16(ah[ks], b, vacc[nt], 0, 0, 0);
        }
    // V tile into Xs (x is dead), bias added in fp32
    #pragma unroll
    for (int nt = 0; nt < 8; ++nt) {
        float bv = Bv[nt * 16 + c];
        #pragma unroll
        for (int i = 0; i < 4; ++i)
            Xs[rw + 4 * g + i][nt * 16 + c] = f2bf(vacc[nt][i] + bv);
    }
    __syncthreads();

    // ---- copy V tile LDS -> global ----
    #pragma unroll
    for (int q = 0; q < 4; ++q) {
        int ch = t + q * 256;
        int r = ch >> 4, off = (ch & 15) << 3;
        *(bf16x8*)(hv_out + (row0 + r) * D + off) = *(const bf16x8*)&Xs[r][off];
    }
}

// ---------------- per-node aggregation: one WAVE per node ----------------
// 256 thr = 4 waves = 4 nodes/block. No LDS, no __syncthreads.
// Softmax passes: 64-lane chunked loads + shfl reduce.
// Accumulate: 2 edges/iter (half-wave each), lane = ushort4 (4 channels, 8B).

__global__ __launch_bounds__(256) void agg_kernel(
    const unsigned short* __restrict__ hb,
    const unsigned short* __restrict__ hvb,
    const float* __restrict__ a,
    const int* __restrict__ row_ptr,
    const int* __restrict__ srcs,
    const float* __restrict__ ln_g, const float* __restrict__ ln_b,
    float* __restrict__ out)
{
    const int t = threadIdx.x;
    const int w = t >> 6, l = t & 63;
    const int flat = blockIdx.x * 4 + w;      // < 40000 (grid is exact)
    const int n = flat % NNODES;
    const int b = flat / NNODES;
    const int bN = b * NNODES;
    const float* ab = a + bN;
    const int e0 = row_ptr[n], e1 = row_ptr[n + 1];
    const int deg = e1 - e0;

    // pass A: segment max
    float m = -1e30f;
    for (int base = e0; base < e1; base += 64) {
        int idx = base + l;
        bool val = idx < e1;
        int sr = srcs[val ? idx : e1 - 1];
        float av = ab[sr];
        m = fmaxf(m, val ? av : -1e30f);
    }
    #pragma unroll
    for (int off = 32; off >= 1; off >>= 1) m = fmaxf(m, __shfl_xor(m, off, 64));

    // pass B: sum of exp
    float s = 0.f;
    for (int base = e0; base < e1; base += 64) {
        int idx = base + l;
        bool val = idx < e1;
        int sr = srcs[val ? idx : e1 - 1];
        float av = ab[sr];
        s += val ? __expf(av - m) : 0.f;
    }
    #pragma unroll
    for (int off = 32; off >= 1; off >>= 1) s += __shfl_xor(s, off, 64);
    const float inv_s = (deg > 0) ? 1.f / s : 0.f;
    const float inv_d = 1.f / (float)max(deg, 1);

    // pass C: weighted V + skip accumulation, 2 edges per iteration
    const int half = l >> 5;
    const int ch4 = l & 31;                   // channel group: channels 4*ch4..+3
    float acc[4] = {0.f, 0.f, 0.f, 0.f};
    float sk [4] = {0.f, 0.f, 0.f, 0.f};

    for (int base = e0; base < e1; base += 64) {
        int cnt = min(64, e1 - base);
        int idx = base + l;
        bool val = idx < e1;
        int sr_l = srcs[val ? idx : e1 - 1];
        float av = ab[sr_l];
        float w_l = val ? __expf(av - m) * inv_s : 0.f;
        for (int jj = 0; jj < ((cnt + 1) >> 1); ++jj) {
            int sel = (jj << 1) + half;
            bool ev = sel < cnt;
            int selc = ev ? sel : cnt - 1;
            int srj  = __shfl(sr_l, selc, 64);
            float wj = __shfl(w_l,  selc, 64);
            wj = ev ? wj : 0.f;
            float skw = ev ? 1.f : 0.f;
            int ofs = (bN + srj) * D + (ch4 << 2);
            ushort4 hv4 = *(const ushort4*)(hvb + ofs);
            ushort4 h4  = *(const ushort4*)(hb + ofs);
            float hvf[4] = { bfu(hv4.x), bfu(hv4.y), bfu(hv4.z), bfu(hv4.w) };
            float hf [4] = { bfu(h4.x),  bfu(h4.y),  bfu(h4.z),  bfu(h4.w) };
            #pragma unroll
            for (int i = 0; i < 4; ++i) {
                acc[i] += wj * hvf[i];
                sk[i]  += skw * hf[i];
            }
        }
    }

    // fold the two halves (lanes l and l^32 hold the same channels)
    #pragma unroll
    for (int i = 0; i < 4; ++i) {
        acc[i] += __shfl_xor(acc[i], 32, 64);
        sk[i]  += __shfl_xor(sk[i],  32, 64);
    }
    float v[4];
    #pragma unroll
    for (int i = 0; i < 4; ++i) v[i] = acc[i] + sk[i] * inv_d;

    // fused LayerNorm over 128 channels (reduce within 32-lane group)
    float sum = v[0] + v[1] + v[2] + v[3];
    float sq  = v[0]*v[0] + v[1]*v[1] + v[2]*v[2] + v[3]*v[3];
    #pragma unroll
    for (int off = 16; off >= 1; off >>= 1) {
        sum += __shfl_xor(sum, off, 64);
        sq  += __shfl_xor(sq,  off, 64);
    }
    float mu   = sum * (1.f / 128.f);
    float var  = sq * (1.f / 128.f) - mu * mu;
    float rstd = rsqrtf(var + EPSF);
    if (half == 0) {
        float4 g  = *(const float4*)(ln_g + (ch4 << 2));
        float4 be = *(const float4*)(ln_b + (ch4 << 2));
        float4 o;
        o.x = (v[0] - mu) * rstd * g.x + be.x;
        o.y = (v[1] - mu) * rstd * g.y + be.y;
        o.z = (v[2] - mu) * rstd * g.z + be.z;
        o.w = (v[3] - mu) * rstd * g.w + be.w;
        *(float4*)(out + (long)flat * D + (ch4 << 2)) = o;
    }
}

// ---------------- launch ----------------

extern "C" void kernel_launch(void* const* d_in, const int* in_sizes, int n_in,
                              void* d_out, int out_size, void* d_ws, size_t ws_size,
                              hipStream_t stream)
{
    const float* x    = (const float*)d_in[0];
    const float* Wp   = (const float*)d_in[1];
    const float* Wq   = (const float*)d_in[2];
    const float* Bq   = (const float*)d_in[3];
    const float* Wk   = (const float*)d_in[4];
    const float* Bk   = (const float*)d_in[5];
    const float* Wv   = (const float*)d_in[6];
    const float* Bv   = (const float*)d_in[7];
    const float* ln_g = (const float*)d_in[8];
    const float* ln_b = (const float*)d_in[9];
    const int*   ei   = (const int*)d_in[10];
    const int* esrc = ei;
    const int* edst = ei + NEDGES;
    float* out = (float*)d_out;

    char* p = (char*)d_ws;
    auto alloc = [&](size_t bytes) -> char* {
        char* r = p;
        p += (bytes + 255) & ~(size_t)255;
        return r;
    };
    unsigned short* hb  = (unsigned short*)alloc((size_t)BATCH * NNODES * D * 2);
    unsigned short* hvb = (unsigned short*)alloc((size_t)BATCH * NNODES * D * 2);
    float* a      = (float*)alloc((size_t)BATCH * NNODES * 4);
    int* counts   = (int*)alloc((size_t)NNODES * 4);
    int* row_ptr  = (int*)alloc((size_t)(NNODES + 1) * 4);
    int* cursor   = (int*)alloc((size_t)NNODES * 4);
    int* srcs     = (int*)alloc((size_t)NEDGES * 4);
    unsigned short* WT = (unsigned short*)alloc((size_t)4 * 128 * 128 * 2);

    hipMemsetAsync(counts, 0, (size_t)NNODES * 4, stream);
    prep_hist_kernel<<<256 + (NEDGES + 255) / 256, 256, 0, stream>>>(Wp, Wq, Wk, Wv, WT, edst, counts);
    scan_kernel<<<1, 1024, 0, stream>>>(counts, row_ptr, cursor);
    scatter_kernel<<<(NEDGES + 255) / 256, 256, 0, stream>>>(esrc, edst, cursor, srcs);
    qkv_mfma_kernel<<<(BATCH * NNODES) / QTILE_M, 256, 0, stream>>>(
        x, WT, Bq, Bk, Bv, hb, hvb, a);
    agg_kernel<<<(BATCH * NNODES) / 4, 256, 0, stream>>>(hb, hvb, a, row_ptr, srcs, ln_g, ln_b, out);
}

// Round 6
// 220.778 us; speedup vs baseline: 1.4308x; 1.1559x over previous
//
#include <hip/hip_runtime.h>
#include <hip/hip_bf16.h>

#define NNODES 20000
#define NEDGES 320000
#define BATCH  2
#define D      128
#define EPSF   1e-5f
#define QTILE_M 64
#define XS_LD   136   // ushorts per Hs row: 128 + 8 pad (272 B stride, 16B-aligned)

typedef __attribute__((ext_vector_type(8))) short bf16x8;
typedef __attribute__((ext_vector_type(4))) float f32x4;

static __device__ __forceinline__ unsigned short f2bf(float f) {
    __hip_bfloat16 h = __float2bfloat16(f);
    return *reinterpret_cast<unsigned short*>(&h);
}
static __device__ __forceinline__ float bfu(unsigned short u) {
    union { unsigned int i; float f; } cv;
    cv.i = ((unsigned int)u) << 16;
    return cv.f;
}

// ---------------- prep (frag-ordered bf16 weights) + histogram ----------------
// blocks [0,32): build WF[mat][frag=nt*4+ks][lane][8] bf16 from fp32 W[k][n]
// blocks [32,...): histogram of dst
__global__ __launch_bounds__(256) void prep_hist_kernel(
    const float* __restrict__ Wp, const float* __restrict__ Wq,
    const float* __restrict__ Wk, const float* __restrict__ Wv,
    unsigned short* __restrict__ WF,
    const int* __restrict__ dst, int* __restrict__ counts)
{
    int bid = blockIdx.x;
    if (bid < 32) {
        int sg = bid * 256 + threadIdx.x;      // slot 0..8191
        int mat = sg >> 11, rem = sg & 2047;
        int f = rem >> 6, l = rem & 63;
        int nt = f >> 2, ks = f & 3;
        int c = l & 15, g = l >> 4;
        const float* W = (mat == 0) ? Wp : (mat == 1) ? Wq : (mat == 2) ? Wk : Wv;
        int n = nt * 16 + c;
        #pragma unroll
        for (int i = 0; i < 8; ++i) {
            int k = ks * 32 + g * 8 + i;
            WF[(size_t)sg * 8 + i] = f2bf(W[k * 128 + n]);
        }
    } else {
        int e = (bid - 32) * 256 + threadIdx.x;
        if (e < NEDGES) atomicAdd(&counts[dst[e]], 1);
    }
}

__global__ __launch_bounds__(1024) void scan_kernel(const int* __restrict__ counts,
                                                    int* __restrict__ row_ptr,
                                                    int* __restrict__ cursor) {
    __shared__ int sd[1024];
    const int t = threadIdx.x;
    const int PER = (NNODES + 1023) / 1024;  // 20
    const int base = t * PER;
    int lsum = 0;
    for (int i = 0; i < PER; ++i) {
        int idx = base + i;
        if (idx < NNODES) lsum += counts[idx];
    }
    sd[t] = lsum;
    __syncthreads();
    for (int off = 1; off < 1024; off <<= 1) {
        int v = sd[t];
        int vp = (t >= off) ? sd[t - off] : 0;
        __syncthreads();
        sd[t] = v + vp;
        __syncthreads();
    }
    int run = sd[t] - lsum;  // exclusive prefix
    for (int i = 0; i < PER; ++i) {
        int idx = base + i;
        if (idx < NNODES) {
            row_ptr[idx] = run;
            cursor[idx]  = run;
            run += counts[idx];
        }
    }
    if (t == 1023) row_ptr[NNODES] = sd[1023];
}

__global__ void scatter_kernel(const int* __restrict__ src, const int* __restrict__ dst,
                               int* __restrict__ cursor, int* __restrict__ srcs) {
    int e = blockIdx.x * blockDim.x + threadIdx.x;
    if (e < NEDGES) {
        int p = atomicAdd(&cursor[dst[e]], 1);
        srcs[p] = src[e];
    }
}

// ---------------- fused per-node QKV via bf16 MFMA, LDS-staged frag-ordered weights ----
// h = x@Wp ; Q = h@Wq+bq ; K = h@Wk+bk ; V = h@Wv+bv ; a = dot(Q,K)*0.25
// 256 thr = 4 waves, 64 rows/block; wave w owns rows [16w,16w+16) x 128 cols.
// Weight staged one matrix at a time (32 KB) into Wbuf; frag reads lane-linear.

__global__ __launch_bounds__(256) void qkv_mfma_kernel(
    const float* __restrict__ x,
    const unsigned short* __restrict__ WF,  // frag-ordered, 4 mats x 16384 ushorts
    const float* __restrict__ Bq, const float* __restrict__ Bk, const float* __restrict__ Bv,
    unsigned short* __restrict__ h_out,
    unsigned short* __restrict__ hv_out,
    float* __restrict__ a_out)
{
    __shared__ unsigned short Wbuf[16384];          // 32 KB
    __shared__ unsigned short Hs[QTILE_M][XS_LD];   // 17.4 KB
    const int t = threadIdx.x;
    const long row0 = (long)blockIdx.x * QTILE_M;
    const int w = t >> 6, l = t & 63;
    const int g = l >> 4, c = l & 15;
    const int rw = w * 16;

    #define STAGE_W(MAT_OFF)                                            \
        _Pragma("unroll")                                               \
        for (int q = 0; q < 8; ++q) {                                   \
            int s = q * 256 + t;                                        \
            *(bf16x8*)&Wbuf[s * 8] = *(const bf16x8*)(WF + (MAT_OFF) + s * 8); \
        }

    // ---- x A-fragments straight from global (fp32 -> bf16) ----
    bf16x8 ax[4];
    {
        const float* xr = x + (row0 + rw + c) * D;
        #pragma unroll
        for (int ks = 0; ks < 4; ++ks) {
            float4 u0 = *(const float4*)(xr + ks * 32 + g * 8);
            float4 u1 = *(const float4*)(xr + ks * 32 + g * 8 + 4);
            bf16x8 f;
            f[0] = (short)f2bf(u0.x); f[1] = (short)f2bf(u0.y);
            f[2] = (short)f2bf(u0.z); f[3] = (short)f2bf(u0.w);
            f[4] = (short)f2bf(u1.x); f[5] = (short)f2bf(u1.y);
            f[6] = (short)f2bf(u1.z); f[7] = (short)f2bf(u1.w);
            ax[ks] = f;
        }
    }

    STAGE_W(0)                      // Wp
    __syncthreads();

    // ---- m1: h = x @ Wp ----
    f32x4 hacc[8];
    #pragma unroll
    for (int nt = 0; nt < 8; ++nt) hacc[nt] = f32x4{0.f, 0.f, 0.f, 0.f};
    #pragma unroll
    for (int nt = 0; nt < 8; ++nt)
        #pragma unroll
        for (int ks = 0; ks < 4; ++ks) {
            bf16x8 b = *(const bf16x8*)&Wbuf[((nt * 4 + ks) * 64 + l) * 8];
            hacc[nt] = __builtin_amdgcn_mfma_f32_16x16x32_bf16(ax[ks], b, hacc[nt], 0, 0, 0);
        }
    #pragma unroll
    for (int nt = 0; nt < 8; ++nt)
        #pragma unroll
        for (int i = 0; i < 4; ++i)
            Hs[rw + 4 * g + i][nt * 16 + c] = f2bf(hacc[nt][i]);
    __syncthreads();

    // ---- h tile -> global (coalesced), A-frags of h, stage Wq ----
    #pragma unroll
    for (int q = 0; q < 4; ++q) {
        int ch = t + q * 256;
        int r = ch >> 4, off = (ch & 15) << 3;
        *(bf16x8*)(h_out + (row0 + r) * D + off) = *(const bf16x8*)&Hs[r][off];
    }
    bf16x8 ah[4];
    #pragma unroll
    for (int ks = 0; ks < 4; ++ks)
        ah[ks] = *(const bf16x8*)&Hs[rw + c][ks * 32 + g * 8];
    STAGE_W(16384)                  // Wq
    __syncthreads();

    // ---- mQ ----
    f32x4 qacc[8];
    #pragma unroll
    for (int nt = 0; nt < 8; ++nt) qacc[nt] = f32x4{0.f, 0.f, 0.f, 0.f};
    #pragma unroll
    for (int nt = 0; nt < 8; ++nt)
        #pragma unroll
        for (int ks = 0; ks < 4; ++ks) {
            bf16x8 b = *(const bf16x8*)&Wbuf[((nt * 4 + ks) * 64 + l) * 8];
            qacc[nt] = __builtin_amdgcn_mfma_f32_16x16x32_bf16(ah[ks], b, qacc[nt], 0, 0, 0);
        }
    __syncthreads();
    STAGE_W(32768)                  // Wk
    __syncthreads();

    // ---- mK + alpha ----
    f32x4 kacc[8];
    #pragma unroll
    for (int nt = 0; nt < 8; ++nt) kacc[nt] = f32x4{0.f, 0.f, 0.f, 0.f};
    #pragma unroll
    for (int nt = 0; nt < 8; ++nt)
        #pragma unroll
        for (int ks = 0; ks < 4; ++ks) {
            bf16x8 b = *(const bf16x8*)&Wbuf[((nt * 4 + ks) * 64 + l) * 8];
            kacc[nt] = __builtin_amdgcn_mfma_f32_16x16x32_bf16(ah[ks], b, kacc[nt], 0, 0, 0);
        }
    {
        float p[4] = {0.f, 0.f, 0.f, 0.f};
        #pragma unroll
        for (int nt = 0; nt < 8; ++nt) {
            float bq = Bq[nt * 16 + c];
            float bk = Bk[nt * 16 + c];
            #pragma unroll
            for (int i = 0; i < 4; ++i)
                p[i] += (qacc[nt][i] + bq) * (kacc[nt][i] + bk);
        }
        #pragma unroll
        for (int off = 1; off < 16; off <<= 1)
            #pragma unroll
            for (int i = 0; i < 4; ++i) p[i] += __shfl_xor(p[i], off, 64);
        if (c == 0)
            #pragma unroll
            for (int i = 0; i < 4; ++i)
                a_out[row0 + rw + 4 * g + i] = p[i] * 0.25f;
    }
    __syncthreads();
    STAGE_W(49152)                  // Wv
    __syncthreads();

    // ---- mV ----
    f32x4 vacc[8];
    #pragma unroll
    for (int nt = 0; nt < 8; ++nt) vacc[nt] = f32x4{0.f, 0.f, 0.f, 0.f};
    #pragma unroll
    for (int nt = 0; nt < 8; ++nt)
        #pragma unroll
        for (int ks = 0; ks < 4; ++ks) {
            bf16x8 b = *(const bf16x8*)&Wbuf[((nt * 4 + ks) * 64 + l) * 8];
            vacc[nt] = __builtin_amdgcn_mfma_f32_16x16x32_bf16(ah[ks], b, vacc[nt], 0, 0, 0);
        }
    #pragma unroll
    for (int nt = 0; nt < 8; ++nt) {
        float bv = Bv[nt * 16 + c];
        #pragma unroll
        for (int i = 0; i < 4; ++i)
            Hs[rw + 4 * g + i][nt * 16 + c] = f2bf(vacc[nt][i] + bv);
    }
    __syncthreads();
    #pragma unroll
    for (int q = 0; q < 4; ++q) {
        int ch = t + q * 256;
        int r = ch >> 4, off = (ch & 15) << 3;
        *(bf16x8*)(hv_out + (row0 + r) * D + off) = *(const bf16x8*)&Hs[r][off];
    }
    #undef STAGE_W
}

// ---------------- per-node aggregation: one WAVE per node, 4 edges/iter ----------------
// 256 thr = 4 waves = 4 nodes/block. lane: q4 = edge slot (0..3), cq = channel group (8 ch).

__global__ __launch_bounds__(256) void agg_kernel(
    const unsigned short* __restrict__ hb,
    const unsigned short* __restrict__ hvb,
    const float* __restrict__ a,
    const int* __restrict__ row_ptr,
    const int* __restrict__ srcs,
    const float* __restrict__ ln_g, const float* __restrict__ ln_b,
    float* __restrict__ out)
{
    const int t = threadIdx.x;
    const int w = t >> 6, l = t & 63;
    const int flat = blockIdx.x * 4 + w;
    const int n = flat % NNODES;
    const int b = flat / NNODES;
    const int bN = b * NNODES;
    const float* ab = a + bN;
    const int e0 = row_ptr[n], e1 = row_ptr[n + 1];
    const int deg = e1 - e0;

    // pass A: segment max
    float m = -1e30f;
    for (int base = e0; base < e1; base += 64) {
        int idx = base + l;
        bool val = idx < e1;
        int sr = srcs[val ? idx : e1 - 1];
        float av = ab[sr];
        m = fmaxf(m, val ? av : -1e30f);
    }
    #pragma unroll
    for (int off = 32; off >= 1; off >>= 1) m = fmaxf(m, __shfl_xor(m, off, 64));

    // pass B: sum of exp
    float s = 0.f;
    for (int base = e0; base < e1; base += 64) {
        int idx = base + l;
        bool val = idx < e1;
        int sr = srcs[val ? idx : e1 - 1];
        float av = ab[sr];
        s += val ? __expf(av - m) : 0.f;
    }
    #pragma unroll
    for (int off = 32; off >= 1; off >>= 1) s += __shfl_xor(s, off, 64);
    const float inv_s = (deg > 0) ? 1.f / s : 0.f;
    const float inv_d = 1.f / (float)max(deg, 1);

    // pass C: weighted V + skip accumulation, 4 edges / iteration
    const int q4 = l >> 4;          // edge slot within quad
    const int cq = l & 15;          // channel group: channels 8*cq .. 8*cq+7
    float acc[8] = {0,0,0,0,0,0,0,0};
    float sk [8] = {0,0,0,0,0,0,0,0};

    for (int base = e0; base < e1; base += 64) {
        int cnt = min(64, e1 - base);
        int idx = base + l;
        bool val = idx < e1;
        int sr_l = srcs[val ? idx : e1 - 1];
        float w_l = val ? __expf(ab[sr_l] - m) * inv_s : 0.f;
        int iters = (cnt + 3) >> 2;
        for (int jj = 0; jj < iters; ++jj) {
            int sel = (jj << 2) + q4;
            bool ev = sel < cnt;
            int selc = ev ? sel : 0;
            int srj  = __shfl(sr_l, selc, 64);
            float wj = __shfl(w_l,  selc, 64);
            wj = ev ? wj : 0.f;
            float skw = ev ? 1.f : 0.f;
            long ofs = (long)(bN + srj) * D + (cq << 3);
            bf16x8 hv8 = *(const bf16x8*)(hvb + ofs);
            bf16x8 h8  = *(const bf16x8*)(hb + ofs);
            #pragma unroll
            for (int i = 0; i < 8; ++i) {
                acc[i] += wj  * bfu((unsigned short)hv8[i]);
                sk[i]  += skw * bfu((unsigned short)h8[i]);
            }
        }
    }

    // fold the 4 quarters (lanes l, l^16, l^32, l^48 hold the same channels)
    #pragma unroll
    for (int i = 0; i < 8; ++i) {
        acc[i] += __shfl_xor(acc[i], 32, 64);
        sk[i]  += __shfl_xor(sk[i],  32, 64);
        acc[i] += __shfl_xor(acc[i], 16, 64);
        sk[i]  += __shfl_xor(sk[i],  16, 64);
    }
    float v[8];
    float sum = 0.f, sq = 0.f;
    #pragma unroll
    for (int i = 0; i < 8; ++i) {
        v[i] = acc[i] + sk[i] * inv_d;
        sum += v[i];
        sq  += v[i] * v[i];
    }
    // LN reduce across the 16-lane channel groups
    #pragma unroll
    for (int off = 8; off >= 1; off >>= 1) {
        sum += __shfl_xor(sum, off, 64);
        sq  += __shfl_xor(sq,  off, 64);
    }
    float mu   = sum * (1.f / 128.f);
    float var  = sq * (1.f / 128.f) - mu * mu;
    float rstd = rsqrtf(var + EPSF);
    if (q4 == 0) {
        float4 g0 = *(const float4*)(ln_g + (cq << 3));
        float4 g1 = *(const float4*)(ln_g + (cq << 3) + 4);
        float4 b0 = *(const float4*)(ln_b + (cq << 3));
        float4 b1 = *(const float4*)(ln_b + (cq << 3) + 4);
        float4 o0, o1;
        o0.x = (v[0] - mu) * rstd * g0.x + b0.x;
        o0.y = (v[1] - mu) * rstd * g0.y + b0.y;
        o0.z = (v[2] - mu) * rstd * g0.z + b0.z;
        o0.w = (v[3] - mu) * rstd * g0.w + b0.w;
        o1.x = (v[4] - mu) * rstd * g1.x + b1.x;
        o1.y = (v[5] - mu) * rstd * g1.y + b1.y;
        o1.z = (v[6] - mu) * rstd * g1.z + b1.z;
        o1.w = (v[7] - mu) * rstd * g1.w + b1.w;
        float* op = out + (long)flat * D + (cq << 3);
        *(float4*)op = o0;
        *(float4*)(op + 4) = o1;
    }
}

// ---------------- launch ----------------

extern "C" void kernel_launch(void* const* d_in, const int* in_sizes, int n_in,
                              void* d_out, int out_size, void* d_ws, size_t ws_size,
                              hipStream_t stream)
{
    const float* x    = (const float*)d_in[0];
    const float* Wp   = (const float*)d_in[1];
    const float* Wq   = (const float*)d_in[2];
    const float* Bq   = (const float*)d_in[3];
    const float* Wk   = (const float*)d_in[4];
    const float* Bk   = (const float*)d_in[5];
    const float* Wv   = (const float*)d_in[6];
    const float* Bv   = (const float*)d_in[7];
    const float* ln_g = (const float*)d_in[8];
    const float* ln_b = (const float*)d_in[9];
    const int*   ei   = (const int*)d_in[10];
    const int* esrc = ei;
    const int* edst = ei + NEDGES;
    float* out = (float*)d_out;

    char* p = (char*)d_ws;
    auto alloc = [&](size_t bytes) -> char* {
        char* r = p;
        p += (bytes + 255) & ~(size_t)255;
        return r;
    };
    unsigned short* hb  = (unsigned short*)alloc((size_t)BATCH * NNODES * D * 2);
    unsigned short* hvb = (unsigned short*)alloc((size_t)BATCH * NNODES * D * 2);
    float* a      = (float*)alloc((size_t)BATCH * NNODES * 4);
    int* counts   = (int*)alloc((size_t)NNODES * 4);
    int* row_ptr  = (int*)alloc((size_t)(NNODES + 1) * 4);
    int* cursor   = (int*)alloc((size_t)NNODES * 4);
    int* srcs     = (int*)alloc((size_t)NEDGES * 4);
    unsigned short* WF = (unsigned short*)alloc((size_t)4 * 128 * 128 * 2);

    hipMemsetAsync(counts, 0, (size_t)NNODES * 4, stream);
    prep_hist_kernel<<<32 + (NEDGES + 255) / 256, 256, 0, stream>>>(Wp, Wq, Wk, Wv, WF, edst, counts);
    scan_kernel<<<1, 1024, 0, stream>>>(counts, row_ptr, cursor);
    scatter_kernel<<<(NEDGES + 255) / 256, 256, 0, stream>>>(esrc, edst, cursor, srcs);
    qkv_mfma_kernel<<<(BATCH * NNODES) / QTILE_M, 256, 0, stream>>>(
        x, WF, Bq, Bk, Bv, hb, hvb, a);
    agg_kernel<<<(BATCH * NNODES) / 4, 256, 0, stream>>>(hb, hvb, a, row_ptr, srcs, ln_g, ln_b, out);
}

// Round 7
// 177.596 us; speedup vs baseline: 1.7787x; 1.2432x over previous
//
#include <hip/hip_runtime.h>
#include <hip/hip_bf16.h>

#define NNODES 20000
#define NEDGES 320000
#define BATCH  2
#define D      128
#define EPSF   1e-5f
#define QTILE_M 64
#define XS_LD   136   // ushorts per Hs row: 128 + 8 pad (272 B stride, 16B-aligned)
#define MAXDEG 64

typedef __attribute__((ext_vector_type(8))) short bf16x8;
typedef __attribute__((ext_vector_type(4))) float f32x4;

static __device__ __forceinline__ unsigned short f2bf(float f) {
    __hip_bfloat16 h = __float2bfloat16(f);
    return *reinterpret_cast<unsigned short*>(&h);
}
static __device__ __forceinline__ float bfu(unsigned short u) {
    union { unsigned int i; float f; } cv;
    cv.i = ((unsigned int)u) << 16;
    return cv.f;
}

// ---------------- prep: frag-ordered bf16 weights (32 blocks) ----------------
__global__ __launch_bounds__(256) void prep_kernel(
    const float* __restrict__ Wp, const float* __restrict__ Wq,
    const float* __restrict__ Wk, const float* __restrict__ Wv,
    unsigned short* __restrict__ WF)
{
    int sg = blockIdx.x * 256 + threadIdx.x;   // slot 0..8191
    int mat = sg >> 11, rem = sg & 2047;
    int f = rem >> 6, l = rem & 63;
    int nt = f >> 2, ks = f & 3;
    int c = l & 15, g = l >> 4;
    const float* W = (mat == 0) ? Wp : (mat == 1) ? Wq : (mat == 2) ? Wk : Wv;
    int n = nt * 16 + c;
    #pragma unroll
    for (int i = 0; i < 8; ++i) {
        int k = ks * 32 + g * 8 + i;
        WF[(size_t)sg * 8 + i] = f2bf(W[k * 128 + n]);
    }
}

// ---------------- padded-CSR scatter + alpha pre-gather (runs AFTER qkv) ----------------
__global__ __launch_bounds__(256) void scatter_pad_kernel(
    const int* __restrict__ src, const int* __restrict__ dst,
    const float* __restrict__ a,          // [BATCH][NNODES]
    int* __restrict__ cursor,             // zeroed; exits holding deg
    int* __restrict__ srcs_pad,           // [NNODES][MAXDEG]
    float* __restrict__ aval)             // [BATCH][NNODES][MAXDEG]
{
    int e = blockIdx.x * 256 + threadIdx.x;
    if (e >= NEDGES) return;
    int d = dst[e], s = src[e];
    int slot = atomicAdd(&cursor[d], 1);
    if (slot < MAXDEG) {
        int p = d * MAXDEG + slot;
        srcs_pad[p] = s;
        aval[p] = a[s];
        aval[NNODES * MAXDEG + p] = a[NNODES + s];
    }
}

// ---------------- fused per-node QKV via bf16 MFMA, LDS-staged frag-ordered weights ----
__global__ __launch_bounds__(256) void qkv_mfma_kernel(
    const float* __restrict__ x,
    const unsigned short* __restrict__ WF,
    const float* __restrict__ Bq, const float* __restrict__ Bk, const float* __restrict__ Bv,
    unsigned short* __restrict__ h_out,
    unsigned short* __restrict__ hv_out,
    float* __restrict__ a_out)
{
    __shared__ unsigned short Wbuf[16384];          // 32 KB
    __shared__ unsigned short Hs[QTILE_M][XS_LD];   // 17.4 KB
    const int t = threadIdx.x;
    const long row0 = (long)blockIdx.x * QTILE_M;
    const int w = t >> 6, l = t & 63;
    const int g = l >> 4, c = l & 15;
    const int rw = w * 16;

    #define STAGE_W(MAT_OFF)                                            \
        _Pragma("unroll")                                               \
        for (int q = 0; q < 8; ++q) {                                   \
            int s = q * 256 + t;                                        \
            *(bf16x8*)&Wbuf[s * 8] = *(const bf16x8*)(WF + (MAT_OFF) + s * 8); \
        }

    // ---- x A-fragments straight from global (fp32 -> bf16) ----
    bf16x8 ax[4];
    {
        const float* xr = x + (row0 + rw + c) * D;
        #pragma unroll
        for (int ks = 0; ks < 4; ++ks) {
            float4 u0 = *(const float4*)(xr + ks * 32 + g * 8);
            float4 u1 = *(const float4*)(xr + ks * 32 + g * 8 + 4);
            bf16x8 f;
            f[0] = (short)f2bf(u0.x); f[1] = (short)f2bf(u0.y);
            f[2] = (short)f2bf(u0.z); f[3] = (short)f2bf(u0.w);
            f[4] = (short)f2bf(u1.x); f[5] = (short)f2bf(u1.y);
            f[6] = (short)f2bf(u1.z); f[7] = (short)f2bf(u1.w);
            ax[ks] = f;
        }
    }

    STAGE_W(0)                      // Wp
    __syncthreads();

    // ---- m1: h = x @ Wp ----
    f32x4 hacc[8];
    #pragma unroll
    for (int nt = 0; nt < 8; ++nt) hacc[nt] = f32x4{0.f, 0.f, 0.f, 0.f};
    #pragma unroll
    for (int nt = 0; nt < 8; ++nt)
        #pragma unroll
        for (int ks = 0; ks < 4; ++ks) {
            bf16x8 b = *(const bf16x8*)&Wbuf[((nt * 4 + ks) * 64 + l) * 8];
            hacc[nt] = __builtin_amdgcn_mfma_f32_16x16x32_bf16(ax[ks], b, hacc[nt], 0, 0, 0);
        }
    #pragma unroll
    for (int nt = 0; nt < 8; ++nt)
        #pragma unroll
        for (int i = 0; i < 4; ++i)
            Hs[rw + 4 * g + i][nt * 16 + c] = f2bf(hacc[nt][i]);
    __syncthreads();

    // ---- h tile -> global (coalesced), A-frags of h, stage Wq ----
    #pragma unroll
    for (int q = 0; q < 4; ++q) {
        int ch = t + q * 256;
        int r = ch >> 4, off = (ch & 15) << 3;
        *(bf16x8*)(h_out + (row0 + r) * D + off) = *(const bf16x8*)&Hs[r][off];
    }
    bf16x8 ah[4];
    #pragma unroll
    for (int ks = 0; ks < 4; ++ks)
        ah[ks] = *(const bf16x8*)&Hs[rw + c][ks * 32 + g * 8];
    STAGE_W(16384)                  // Wq
    __syncthreads();

    // ---- mQ ----
    f32x4 qacc[8];
    #pragma unroll
    for (int nt = 0; nt < 8; ++nt) qacc[nt] = f32x4{0.f, 0.f, 0.f, 0.f};
    #pragma unroll
    for (int nt = 0; nt < 8; ++nt)
        #pragma unroll
        for (int ks = 0; ks < 4; ++ks) {
            bf16x8 b = *(const bf16x8*)&Wbuf[((nt * 4 + ks) * 64 + l) * 8];
            qacc[nt] = __builtin_amdgcn_mfma_f32_16x16x32_bf16(ah[ks], b, qacc[nt], 0, 0, 0);
        }
    __syncthreads();
    STAGE_W(32768)                  // Wk
    __syncthreads();

    // ---- mK ----
    f32x4 kacc[8];
    #pragma unroll
    for (int nt = 0; nt < 8; ++nt) kacc[nt] = f32x4{0.f, 0.f, 0.f, 0.f};
    #pragma unroll
    for (int nt = 0; nt < 8; ++nt)
        #pragma unroll
        for (int ks = 0; ks < 4; ++ks) {
            bf16x8 b = *(const bf16x8*)&Wbuf[((nt * 4 + ks) * 64 + l) * 8];
            kacc[nt] = __builtin_amdgcn_mfma_f32_16x16x32_bf16(ah[ks], b, kacc[nt], 0, 0, 0);
        }
    __syncthreads();
    STAGE_W(49152)                  // Wv (loads in flight while alpha computes below)

    // ---- alpha = dot(Q+bq, K+bk)*0.25 (VALU, overlapped with Wv staging) ----
    {
        float p[4] = {0.f, 0.f, 0.f, 0.f};
        #pragma unroll
        for (int nt = 0; nt < 8; ++nt) {
            float bq = Bq[nt * 16 + c];
            float bk = Bk[nt * 16 + c];
            #pragma unroll
            for (int i = 0; i < 4; ++i)
                p[i] += (qacc[nt][i] + bq) * (kacc[nt][i] + bk);
        }
        #pragma unroll
        for (int off = 1; off < 16; off <<= 1)
            #pragma unroll
            for (int i = 0; i < 4; ++i) p[i] += __shfl_xor(p[i], off, 64);
        if (c == 0)
            #pragma unroll
            for (int i = 0; i < 4; ++i)
                a_out[row0 + rw + 4 * g + i] = p[i] * 0.25f;
    }
    __syncthreads();

    // ---- mV ----
    f32x4 vacc[8];
    #pragma unroll
    for (int nt = 0; nt < 8; ++nt) vacc[nt] = f32x4{0.f, 0.f, 0.f, 0.f};
    #pragma unroll
    for (int nt = 0; nt < 8; ++nt)
        #pragma unroll
        for (int ks = 0; ks < 4; ++ks) {
            bf16x8 b = *(const bf16x8*)&Wbuf[((nt * 4 + ks) * 64 + l) * 8];
            vacc[nt] = __builtin_amdgcn_mfma_f32_16x16x32_bf16(ah[ks], b, vacc[nt], 0, 0, 0);
        }
    #pragma unroll
    for (int nt = 0; nt < 8; ++nt) {
        float bv = Bv[nt * 16 + c];
        #pragma unroll
        for (int i = 0; i < 4; ++i)
            Hs[rw + 4 * g + i][nt * 16 + c] = f2bf(vacc[nt][i] + bv);
    }
    __syncthreads();
    #pragma unroll
    for (int q = 0; q < 4; ++q) {
        int ch = t + q * 256;
        int r = ch >> 4, off = (ch & 15) << 3;
        *(bf16x8*)(hv_out + (row0 + r) * D + off) = *(const bf16x8*)&Hs[r][off];
    }
    #undef STAGE_W
}

// ---------------- aggregation: one WAVE per node, padded CSR, register softmax ----------------
// 256 thr = 4 waves = 4 nodes/block. deg <= 64 guaranteed -> single chunk in registers.

__global__ __launch_bounds__(256) void agg_kernel(
    const unsigned short* __restrict__ hb,
    const unsigned short* __restrict__ hvb,
    const float* __restrict__ aval,       // [BATCH][NNODES][MAXDEG]
    const int* __restrict__ deg_arr,      // cursor after scatter
    const int* __restrict__ srcs_pad,     // [NNODES][MAXDEG]
    const float* __restrict__ ln_g, const float* __restrict__ ln_b,
    float* __restrict__ out)
{
    const int t = threadIdx.x;
    const int w = t >> 6, l = t & 63;
    const int flat = blockIdx.x * 4 + w;
    const int n = flat % NNODES;
    const int b = flat / NNODES;
    const int bN = b * NNODES;
    const int deg = min(deg_arr[n], MAXDEG);
    const int base = n * MAXDEG;
    const bool valid = l < deg;

    // coalesced loads of this segment's srcs + alpha (one chunk, register-held)
    int   sr_l = valid ? srcs_pad[base + l] : 0;
    float av_l = valid ? aval[b * (NNODES * MAXDEG) + base + l] : -1e30f;

    // softmax stats in-register
    float m = av_l;
    #pragma unroll
    for (int off = 32; off >= 1; off >>= 1) m = fmaxf(m, __shfl_xor(m, off, 64));
    float e_l = valid ? __expf(av_l - m) : 0.f;
    float s = e_l;
    #pragma unroll
    for (int off = 32; off >= 1; off >>= 1) s += __shfl_xor(s, off, 64);
    const float inv_s = (deg > 0) ? 1.f / s : 0.f;
    const float inv_d = 1.f / (float)max(deg, 1);
    const float w_l = e_l * inv_s;

    // weighted V + skip accumulation, 4 edges / iteration
    const int q4 = l >> 4;          // edge slot within quad
    const int cq = l & 15;          // channel group: channels 8*cq .. 8*cq+7
    float acc[8] = {0,0,0,0,0,0,0,0};
    float sk [8] = {0,0,0,0,0,0,0,0};
    const long rowArr = (long)bN * D;

    const int iters = (deg + 3) >> 2;
    for (int jj = 0; jj < iters; ++jj) {
        int sel = (jj << 2) + q4;
        bool ev = sel < deg;
        int selc = ev ? sel : 0;
        int srj  = __shfl(sr_l, selc, 64);
        float wj = __shfl(w_l,  selc, 64);
        wj = ev ? wj : 0.f;
        float skw = ev ? 1.f : 0.f;
        long ofs = rowArr + (long)srj * D + (cq << 3);
        bf16x8 hv8 = *(const bf16x8*)(hvb + ofs);
        bf16x8 h8  = *(const bf16x8*)(hb + ofs);
        #pragma unroll
        for (int i = 0; i < 8; ++i) {
            acc[i] += wj  * bfu((unsigned short)hv8[i]);
            sk[i]  += skw * bfu((unsigned short)h8[i]);
        }
    }

    // fold the 4 quarters (lanes l, l^16, l^32, l^48 hold the same channels)
    #pragma unroll
    for (int i = 0; i < 8; ++i) {
        acc[i] += __shfl_xor(acc[i], 32, 64);
        sk[i]  += __shfl_xor(sk[i],  32, 64);
        acc[i] += __shfl_xor(acc[i], 16, 64);
        sk[i]  += __shfl_xor(sk[i],  16, 64);
    }
    float v[8];
    float sum = 0.f, sq = 0.f;
    #pragma unroll
    for (int i = 0; i < 8; ++i) {
        v[i] = acc[i] + sk[i] * inv_d;
        sum += v[i];
        sq  += v[i] * v[i];
    }
    #pragma unroll
    for (int off = 8; off >= 1; off >>= 1) {
        sum += __shfl_xor(sum, off, 64);
        sq  += __shfl_xor(sq,  off, 64);
    }
    float mu   = sum * (1.f / 128.f);
    float var  = sq * (1.f / 128.f) - mu * mu;
    float rstd = rsqrtf(var + EPSF);
    if (q4 == 0) {
        float4 g0 = *(const float4*)(ln_g + (cq << 3));
        float4 g1 = *(const float4*)(ln_g + (cq << 3) + 4);
        float4 b0 = *(const float4*)(ln_b + (cq << 3));
        float4 b1 = *(const float4*)(ln_b + (cq << 3) + 4);
        float4 o0, o1;
        o0.x = (v[0] - mu) * rstd * g0.x + b0.x;
        o0.y = (v[1] - mu) * rstd * g0.y + b0.y;
        o0.z = (v[2] - mu) * rstd * g0.z + b0.z;
        o0.w = (v[3] - mu) * rstd * g0.w + b0.w;
        o1.x = (v[4] - mu) * rstd * g1.x + b1.x;
        o1.y = (v[5] - mu) * rstd * g1.y + b1.y;
        o1.z = (v[6] - mu) * rstd * g1.z + b1.z;
        o1.w = (v[7] - mu) * rstd * g1.w + b1.w;
        float* op = out + (long)flat * D + (cq << 3);
        *(float4*)op = o0;
        *(float4*)(op + 4) = o1;
    }
}

// ---------------- launch ----------------

extern "C" void kernel_launch(void* const* d_in, const int* in_sizes, int n_in,
                              void* d_out, int out_size, void* d_ws, size_t ws_size,
                              hipStream_t stream)
{
    const float* x    = (const float*)d_in[0];
    const float* Wp   = (const float*)d_in[1];
    const float* Wq   = (const float*)d_in[2];
    const float* Bq   = (const float*)d_in[3];
    const float* Wk   = (const float*)d_in[4];
    const float* Bk   = (const float*)d_in[5];
    const float* Wv   = (const float*)d_in[6];
    const float* Bv   = (const float*)d_in[7];
    const float* ln_g = (const float*)d_in[8];
    const float* ln_b = (const float*)d_in[9];
    const int*   ei   = (const int*)d_in[10];
    const int* esrc = ei;
    const int* edst = ei + NEDGES;
    float* out = (float*)d_out;

    char* p = (char*)d_ws;
    auto alloc = [&](size_t bytes) -> char* {
        char* r = p;
        p += (bytes + 255) & ~(size_t)255;
        return r;
    };
    unsigned short* hb  = (unsigned short*)alloc((size_t)BATCH * NNODES * D * 2);
    unsigned short* hvb = (unsigned short*)alloc((size_t)BATCH * NNODES * D * 2);
    float* a        = (float*)alloc((size_t)BATCH * NNODES * 4);
    int* cursor     = (int*)alloc((size_t)NNODES * 4);
    int* srcs_pad   = (int*)alloc((size_t)NNODES * MAXDEG * 4);
    float* aval     = (float*)alloc((size_t)BATCH * NNODES * MAXDEG * 4);
    unsigned short* WF = (unsigned short*)alloc((size_t)4 * 128 * 128 * 2);

    hipMemsetAsync(cursor, 0, (size_t)NNODES * 4, stream);
    prep_kernel<<<32, 256, 0, stream>>>(Wp, Wq, Wk, Wv, WF);
    qkv_mfma_kernel<<<(BATCH * NNODES) / QTILE_M, 256, 0, stream>>>(
        x, WF, Bq, Bk, Bv, hb, hvb, a);
    scatter_pad_kernel<<<(NEDGES + 255) / 256, 256, 0, stream>>>(
        esrc, edst, a, cursor, srcs_pad, aval);
    agg_kernel<<<(BATCH * NNODES) / 4, 256, 0, stream>>>(
        hb, hvb, aval, cursor, srcs_pad, ln_g, ln_b, out);
}

// Round 8
// 164.437 us; speedup vs baseline: 1.9210x; 1.0800x over previous
//
#include <hip/hip_runtime.h>
#include <hip/hip_bf16.h>

#define NNODES 20000
#define NEDGES 320000
#define BATCH  2
#define D      128
#define EPSF   1e-5f
#define QTILE_M 64
#define XS_LD   136   // ushorts per Hs row: 128 + 8 pad
#define MAXDEG 64

typedef __attribute__((ext_vector_type(8))) short bf16x8;
typedef __attribute__((ext_vector_type(4))) float f32x4;

static __device__ __forceinline__ unsigned short f2bf(float f) {
    __hip_bfloat16 h = __float2bfloat16(f);
    return *reinterpret_cast<unsigned short*>(&h);
}
static __device__ __forceinline__ float bfu(unsigned short u) {
    union { unsigned int i; float f; } cv;
    cv.i = ((unsigned int)u) << 16;
    return cv.f;
}

// ---------------- prep: frag-ordered bf16 weights (blocks 0..31) + cursor clear (32..110) ----
__global__ __launch_bounds__(256) void prep_kernel(
    const float* __restrict__ Wp, const float* __restrict__ Wq,
    const float* __restrict__ Wk, const float* __restrict__ Wv,
    unsigned short* __restrict__ WF,
    int* __restrict__ cursor)
{
    int bid = blockIdx.x;
    if (bid < 32) {
        int sg = bid * 256 + threadIdx.x;   // slot 0..8191
        int mat = sg >> 11, rem = sg & 2047;
        int f = rem >> 6, l = rem & 63;
        int nt = f >> 2, ks = f & 3;
        int c = l & 15, g = l >> 4;
        const float* W = (mat == 0) ? Wp : (mat == 1) ? Wq : (mat == 2) ? Wk : Wv;
        int n = nt * 16 + c;
        #pragma unroll
        for (int i = 0; i < 8; ++i) {
            int k = ks * 32 + g * 8 + i;
            WF[(size_t)sg * 8 + i] = f2bf(W[k * 128 + n]);
        }
    } else {
        int idx = (bid - 32) * 256 + threadIdx.x;
        if (idx < NNODES) cursor[idx] = 0;
    }
}

// ---------------- padded-CSR scatter (srcs only) ----------------
__global__ __launch_bounds__(256) void scatter_pad_kernel(
    const int* __restrict__ src, const int* __restrict__ dst,
    int* __restrict__ cursor,             // exits holding deg
    int* __restrict__ srcs_pad)           // [NNODES][MAXDEG]
{
    int e = blockIdx.x * 256 + threadIdx.x;
    if (e >= NEDGES) return;
    int d = dst[e], s = src[e];
    int slot = atomicAdd(&cursor[d], 1);
    if (slot < MAXDEG) srcs_pad[d * MAXDEG + slot] = s;
}

// ---------------- fused per-node QKV via bf16 MFMA, reg-prefetched weight staging ----------
// h = x@Wp ; Q = h@Wq+bq ; K = h@Wk+bk ; V = h@Wv+bv ; a = dot(Q,K)*0.25
// hhv layout: [row][0..127]=h, [row][128..255]=V  (bf16)

__global__ __launch_bounds__(256) void qkv_mfma_kernel(
    const float* __restrict__ x,
    const unsigned short* __restrict__ WF,
    const float* __restrict__ Bq, const float* __restrict__ Bk, const float* __restrict__ Bv,
    unsigned short* __restrict__ hhv,
    float* __restrict__ a_out)
{
    __shared__ unsigned short Wbuf[16384];          // 32 KB
    __shared__ unsigned short Hs[QTILE_M][XS_LD];   // 17.4 KB
    const int t = threadIdx.x;
    const long row0 = (long)blockIdx.x * QTILE_M;
    const int w = t >> 6, l = t & 63;
    const int g = l >> 4, c = l & 15;
    const int rw = w * 16;

    bf16x8 wreg[8];
    #define LOAD_W_REGS(MAT_OFF)                                        \
        _Pragma("unroll")                                               \
        for (int q = 0; q < 8; ++q)                                     \
            wreg[q] = *(const bf16x8*)(WF + (MAT_OFF) + (q * 256 + t) * 8);
    #define WRITE_W_LDS()                                               \
        _Pragma("unroll")                                               \
        for (int q = 0; q < 8; ++q)                                     \
            *(bf16x8*)&Wbuf[(q * 256 + t) * 8] = wreg[q];

    LOAD_W_REGS(0)                  // Wp -> regs

    // ---- x A-fragments straight from global (fp32 -> bf16) ----
    bf16x8 ax[4];
    {
        const float* xr = x + (row0 + rw + c) * D;
        #pragma unroll
        for (int ks = 0; ks < 4; ++ks) {
            float4 u0 = *(const float4*)(xr + ks * 32 + g * 8);
            float4 u1 = *(const float4*)(xr + ks * 32 + g * 8 + 4);
            bf16x8 f;
            f[0] = (short)f2bf(u0.x); f[1] = (short)f2bf(u0.y);
            f[2] = (short)f2bf(u0.z); f[3] = (short)f2bf(u0.w);
            f[4] = (short)f2bf(u1.x); f[5] = (short)f2bf(u1.y);
            f[6] = (short)f2bf(u1.z); f[7] = (short)f2bf(u1.w);
            ax[ks] = f;
        }
    }

    WRITE_W_LDS();                  // Wp -> LDS
    __syncthreads();
    LOAD_W_REGS(16384)              // prefetch Wq during m1

    // ---- m1: h = x @ Wp ----
    f32x4 hacc[8];
    #pragma unroll
    for (int nt = 0; nt < 8; ++nt) hacc[nt] = f32x4{0.f, 0.f, 0.f, 0.f};
    #pragma unroll
    for (int nt = 0; nt < 8; ++nt)
        #pragma unroll
        for (int ks = 0; ks < 4; ++ks) {
            bf16x8 b = *(const bf16x8*)&Wbuf[((nt * 4 + ks) * 64 + l) * 8];
            hacc[nt] = __builtin_amdgcn_mfma_f32_16x16x32_bf16(ax[ks], b, hacc[nt], 0, 0, 0);
        }
    #pragma unroll
    for (int nt = 0; nt < 8; ++nt)
        #pragma unroll
        for (int i = 0; i < 4; ++i)
            Hs[rw + 4 * g + i][nt * 16 + c] = f2bf(hacc[nt][i]);
    __syncthreads();                // h tile complete; everyone past m1 (Wbuf free)

    // ---- h half-rows -> global, A-frags of h ----
    #pragma unroll
    for (int q = 0; q < 4; ++q) {
        int ch = t + q * 256;
        int r = ch >> 4, off = (ch & 15) << 3;
        *(bf16x8*)(hhv + (row0 + r) * 256 + off) = *(const bf16x8*)&Hs[r][off];
    }
    bf16x8 ah[4];
    #pragma unroll
    for (int ks = 0; ks < 4; ++ks)
        ah[ks] = *(const bf16x8*)&Hs[rw + c][ks * 32 + g * 8];

    WRITE_W_LDS();                  // Wq -> LDS
    __syncthreads();
    LOAD_W_REGS(32768)              // prefetch Wk during mQ

    // ---- mQ ----
    f32x4 qacc[8];
    #pragma unroll
    for (int nt = 0; nt < 8; ++nt) qacc[nt] = f32x4{0.f, 0.f, 0.f, 0.f};
    #pragma unroll
    for (int nt = 0; nt < 8; ++nt)
        #pragma unroll
        for (int ks = 0; ks < 4; ++ks) {
            bf16x8 b = *(const bf16x8*)&Wbuf[((nt * 4 + ks) * 64 + l) * 8];
            qacc[nt] = __builtin_amdgcn_mfma_f32_16x16x32_bf16(ah[ks], b, qacc[nt], 0, 0, 0);
        }
    __syncthreads();                // all done reading Wq

    WRITE_W_LDS();                  // Wk -> LDS
    __syncthreads();
    LOAD_W_REGS(49152)              // prefetch Wv during mK

    // ---- mK ----
    f32x4 kacc[8];
    #pragma unroll
    for (int nt = 0; nt < 8; ++nt) kacc[nt] = f32x4{0.f, 0.f, 0.f, 0.f};
    #pragma unroll
    for (int nt = 0; nt < 8; ++nt)
        #pragma unroll
        for (int ks = 0; ks < 4; ++ks) {
            bf16x8 b = *(const bf16x8*)&Wbuf[((nt * 4 + ks) * 64 + l) * 8];
            kacc[nt] = __builtin_amdgcn_mfma_f32_16x16x32_bf16(ah[ks], b, kacc[nt], 0, 0, 0);
        }
    __syncthreads();                // all done reading Wk

    WRITE_W_LDS();                  // Wv -> LDS
    __syncthreads();

    // ---- alpha = dot(Q+bq, K+bk)*0.25 (VALU while mV could proceed on other waves) ----
    {
        float p[4] = {0.f, 0.f, 0.f, 0.f};
        #pragma unroll
        for (int nt = 0; nt < 8; ++nt) {
            float bq = Bq[nt * 16 + c];
            float bk = Bk[nt * 16 + c];
            #pragma unroll
            for (int i = 0; i < 4; ++i)
                p[i] += (qacc[nt][i] + bq) * (kacc[nt][i] + bk);
        }
        #pragma unroll
        for (int off = 1; off < 16; off <<= 1)
            #pragma unroll
            for (int i = 0; i < 4; ++i) p[i] += __shfl_xor(p[i], off, 64);
        if (c == 0)
            #pragma unroll
            for (int i = 0; i < 4; ++i)
                a_out[row0 + rw + 4 * g + i] = p[i] * 0.25f;
    }

    // ---- mV ----
    f32x4 vacc[8];
    #pragma unroll
    for (int nt = 0; nt < 8; ++nt) vacc[nt] = f32x4{0.f, 0.f, 0.f, 0.f};
    #pragma unroll
    for (int nt = 0; nt < 8; ++nt)
        #pragma unroll
        for (int ks = 0; ks < 4; ++ks) {
            bf16x8 b = *(const bf16x8*)&Wbuf[((nt * 4 + ks) * 64 + l) * 8];
            vacc[nt] = __builtin_amdgcn_mfma_f32_16x16x32_bf16(ah[ks], b, vacc[nt], 0, 0, 0);
        }
    #pragma unroll
    for (int nt = 0; nt < 8; ++nt) {
        float bv = Bv[nt * 16 + c];
        #pragma unroll
        for (int i = 0; i < 4; ++i)
            Hs[rw + 4 * g + i][nt * 16 + c] = f2bf(vacc[nt][i] + bv);
    }
    __syncthreads();
    #pragma unroll
    for (int q = 0; q < 4; ++q) {
        int ch = t + q * 256;
        int r = ch >> 4, off = (ch & 15) << 3;
        *(bf16x8*)(hhv + (row0 + r) * 256 + 128 + off) = *(const bf16x8*)&Hs[r][off];
    }
    #undef LOAD_W_REGS
    #undef WRITE_W_LDS
}

// ---------------- aggregation: one WAVE per node, padded CSR, register softmax ----------------
// 256 thr = 4 waves = 4 nodes/block. deg <= 64 -> single register chunk.
// Gather loop 2-deep software-pipelined; hhv row = 512 B contiguous (h | hv).

__global__ __launch_bounds__(256) void agg_kernel(
    const unsigned short* __restrict__ hhv,
    const float* __restrict__ a,          // [BATCH][NNODES]
    const int* __restrict__ deg_arr,
    const int* __restrict__ srcs_pad,     // [NNODES][MAXDEG]
    const float* __restrict__ ln_g, const float* __restrict__ ln_b,
    float* __restrict__ out)
{
    const int t = threadIdx.x;
    const int w = t >> 6, l = t & 63;
    const int flat = blockIdx.x * 4 + w;
    const int n = flat % NNODES;
    const int b = flat / NNODES;
    const int bN = b * NNODES;
    const int deg = min(deg_arr[n], MAXDEG);
    const bool valid = l < deg;

    // coalesced srcs load, L2-resident alpha gather
    int   sr_l = valid ? srcs_pad[n * MAXDEG + l] : 0;
    float av_l = valid ? a[bN + sr_l] : -1e30f;

    // softmax stats in-register
    float m = av_l;
    #pragma unroll
    for (int off = 32; off >= 1; off >>= 1) m = fmaxf(m, __shfl_xor(m, off, 64));
    float e_l = valid ? __expf(av_l - m) : 0.f;
    float s = e_l;
    #pragma unroll
    for (int off = 32; off >= 1; off >>= 1) s += __shfl_xor(s, off, 64);
    const float inv_s = (deg > 0) ? 1.f / s : 0.f;
    const float inv_d = 1.f / (float)max(deg, 1);
    const float w_l = e_l * inv_s;

    const int q4 = l >> 4;          // edge slot within quad
    const int cq = l & 15;          // channel group: channels 8*cq..+7
    float acc[8] = {0,0,0,0,0,0,0,0};
    float sk [8] = {0,0,0,0,0,0,0,0};
    const long rowArr = (long)bN * 256 + (cq << 3);

    if (deg > 0) {
        const int iters = (deg + 3) >> 2;
        // prologue: slot q4
        long of0; float wj0, sw0;
        {
            int sel = q4;
            bool ev = sel < deg;
            int selc = ev ? sel : 0;
            int srj = __shfl(sr_l, selc, 64);
            float wj = __shfl(w_l, selc, 64);
            wj0 = ev ? wj : 0.f;
            sw0 = ev ? 1.f : 0.f;
            of0 = rowArr + (long)srj * 256;
        }
        bf16x8 h0  = *(const bf16x8*)(hhv + of0);
        bf16x8 hv0 = *(const bf16x8*)(hhv + of0 + 128);
        for (int jj = 0; jj < iters - 1; ++jj) {
            // prepare + issue loads for jj+1
            long of1; float wj1, sw1;
            {
                int sel = ((jj + 1) << 2) + q4;
                bool ev = sel < deg;
                int selc = ev ? sel : 0;
                int srj = __shfl(sr_l, selc, 64);
                float wj = __shfl(w_l, selc, 64);
                wj1 = ev ? wj : 0.f;
                sw1 = ev ? 1.f : 0.f;
                of1 = rowArr + (long)srj * 256;
            }
            bf16x8 h1  = *(const bf16x8*)(hhv + of1);
            bf16x8 hv1 = *(const bf16x8*)(hhv + of1 + 128);
            // accumulate jj
            #pragma unroll
            for (int i = 0; i < 8; ++i) {
                acc[i] += wj0 * bfu((unsigned short)hv0[i]);
                sk[i]  += sw0 * bfu((unsigned short)h0[i]);
            }
            h0 = h1; hv0 = hv1; wj0 = wj1; sw0 = sw1;
        }
        #pragma unroll
        for (int i = 0; i < 8; ++i) {
            acc[i] += wj0 * bfu((unsigned short)hv0[i]);
            sk[i]  += sw0 * bfu((unsigned short)h0[i]);
        }
    }

    // fold the 4 quarters (lanes l, l^16, l^32, l^48 hold the same channels)
    #pragma unroll
    for (int i = 0; i < 8; ++i) {
        acc[i] += __shfl_xor(acc[i], 32, 64);
        sk[i]  += __shfl_xor(sk[i],  32, 64);
        acc[i] += __shfl_xor(acc[i], 16, 64);
        sk[i]  += __shfl_xor(sk[i],  16, 64);
    }
    float v[8];
    float sum = 0.f, sq = 0.f;
    #pragma unroll
    for (int i = 0; i < 8; ++i) {
        v[i] = acc[i] + sk[i] * inv_d;
        sum += v[i];
        sq  += v[i] * v[i];
    }
    #pragma unroll
    for (int off = 8; off >= 1; off >>= 1) {
        sum += __shfl_xor(sum, off, 64);
        sq  += __shfl_xor(sq,  off, 64);
    }
    float mu   = sum * (1.f / 128.f);
    float var  = sq * (1.f / 128.f) - mu * mu;
    float rstd = rsqrtf(var + EPSF);
    if (q4 == 0) {
        float4 g0 = *(const float4*)(ln_g + (cq << 3));
        float4 g1 = *(const float4*)(ln_g + (cq << 3) + 4);
        float4 b0 = *(const float4*)(ln_b + (cq << 3));
        float4 b1 = *(const float4*)(ln_b + (cq << 3) + 4);
        float4 o0, o1;
        o0.x = (v[0] - mu) * rstd * g0.x + b0.x;
        o0.y = (v[1] - mu) * rstd * g0.y + b0.y;
        o0.z = (v[2] - mu) * rstd * g0.z + b0.z;
        o0.w = (v[3] - mu) * rstd * g0.w + b0.w;
        o1.x = (v[4] - mu) * rstd * g1.x + b1.x;
        o1.y = (v[5] - mu) * rstd * g1.y + b1.y;
        o1.z = (v[6] - mu) * rstd * g1.z + b1.z;
        o1.w = (v[7] - mu) * rstd * g1.w + b1.w;
        float* op = out + (long)flat * D + (cq << 3);
        *(float4*)op = o0;
        *(float4*)(op + 4) = o1;
    }
}

// ---------------- launch ----------------

extern "C" void kernel_launch(void* const* d_in, const int* in_sizes, int n_in,
                              void* d_out, int out_size, void* d_ws, size_t ws_size,
                              hipStream_t stream)
{
    const float* x    = (const float*)d_in[0];
    const float* Wp   = (const float*)d_in[1];
    const float* Wq   = (const float*)d_in[2];
    const float* Bq   = (const float*)d_in[3];
    const float* Wk   = (const float*)d_in[4];
    const float* Bk   = (const float*)d_in[5];
    const float* Wv   = (const float*)d_in[6];
    const float* Bv   = (const float*)d_in[7];
    const float* ln_g = (const float*)d_in[8];
    const float* ln_b = (const float*)d_in[9];
    const int*   ei   = (const int*)d_in[10];
    const int* esrc = ei;
    const int* edst = ei + NEDGES;
    float* out = (float*)d_out;

    char* p = (char*)d_ws;
    auto alloc = [&](size_t bytes) -> char* {
        char* r = p;
        p += (bytes + 255) & ~(size_t)255;
        return r;
    };
    unsigned short* hhv = (unsigned short*)alloc((size_t)BATCH * NNODES * 256 * 2);
    float* a        = (float*)alloc((size_t)BATCH * NNODES * 4);
    int* cursor     = (int*)alloc((size_t)NNODES * 4);
    int* srcs_pad   = (int*)alloc((size_t)NNODES * MAXDEG * 4);
    unsigned short* WF = (unsigned short*)alloc((size_t)4 * 128 * 128 * 2);

    prep_kernel<<<111, 256, 0, stream>>>(Wp, Wq, Wk, Wv, WF, cursor);
    scatter_pad_kernel<<<(NEDGES + 255) / 256, 256, 0, stream>>>(esrc, edst, cursor, srcs_pad);
    qkv_mfma_kernel<<<(BATCH * NNODES) / QTILE_M, 256, 0, stream>>>(
        x, WF, Bq, Bk, Bv, hhv, a);
    agg_kernel<<<(BATCH * NNODES) / 4, 256, 0, stream>>>(
        hhv, a, cursor, srcs_pad, ln_g, ln_b, out);
}